// Round 1
// baseline (564.637 us; speedup 1.0000x reference)
//
#include <hip/hip_runtime.h>
#include <math.h>

#define N_USERS 50000
#define N_ENT   200000
#define NTOT    250000
#define D       128
#define E_EDGES 2000000
#define B       8192
#define NCAT    8
#define NNUM    16
#define HDIM    256   // 2*D

__device__ __forceinline__ float sigf(float x) { return 1.0f / (1.0f + expf(-x)); }

// ---------------------------------------------------------------------------
// Build row -> slot map. Users occupy global rows [N_ENT, NTOT), slots [0,B).
// Items occupy rows [0, N_ENT), slots [B, 2B). Duplicates dedup via atomicMax.
__global__ __launch_bounds__(256) void build_map_kernel(
    const int* __restrict__ uids, const int* __restrict__ iids, int* __restrict__ map)
{
    int b = blockIdx.x * 256 + threadIdx.x;
    if (b < B) {
        atomicMax(&map[uids[b] + N_ENT], b);
        atomicMax(&map[iids[b]], B + b);
    }
}

// ---------------------------------------------------------------------------
// Effective (masked) weights: Weff = W * sigmoid(Mw[task]), beff = b * sigmoid(Mb[task])
__global__ __launch_bounds__(256) void weff_kernel(
    const float* __restrict__ W0, const float* __restrict__ Mw0,
    const float* __restrict__ b0, const float* __restrict__ Mb0,
    const float* __restrict__ W1, const float* __restrict__ Mw1,
    const float* __restrict__ b1, const float* __restrict__ Mb1,
    const float* __restrict__ W2, const float* __restrict__ Mw2,
    const float* __restrict__ b2, const float* __restrict__ Mb2,
    float* __restrict__ Weff0, float* __restrict__ Weff1, float* __restrict__ w2eff,
    float* __restrict__ beff0, float* __restrict__ beff1, float* __restrict__ b2eff)
{
    int i = blockIdx.x * 256 + threadIdx.x;
    if (i < 131072) {                     // Weff0: [2][256][256]
        int rem = i & 65535;
        Weff0[i] = W0[rem] * sigf(Mw0[i]);
    } else if (i < 262144) {              // Weff1
        int ii = i - 131072;
        int rem = ii & 65535;
        Weff1[ii] = W1[rem] * sigf(Mw1[ii]);
    } else if (i < 262656) {              // w2eff: [2][256]
        int ii = i - 262144;
        int j = ii & 255;
        w2eff[ii] = W2[j] * sigf(Mw2[ii]);
    } else if (i < 263168) {              // beff0: [2][256]
        int ii = i - 262656;
        int j = ii & 255;
        beff0[ii] = b0[j] * sigf(Mb0[ii]);
    } else if (i < 263680) {              // beff1
        int ii = i - 263168;
        int j = ii & 255;
        beff1[ii] = b1[j] * sigf(Mb1[ii]);
    } else if (i < 263682) {              // b2eff: [2]
        int ii = i - 263680;
        b2eff[ii] = b2[0] * sigf(Mb2[ii]);
    }
}

// ---------------------------------------------------------------------------
// Filter edges whose destination row is needed; compact into elist.
__global__ __launch_bounds__(256) void filter_kernel(
    const int* __restrict__ A_rows, const int* __restrict__ map,
    int* __restrict__ counter, int* __restrict__ elist)
{
    int e = blockIdx.x * 256 + threadIdx.x;
    if (e < E_EDGES) {
        if (map[A_rows[e]] >= 0) {
            int pos = atomicAdd(counter, 1);
            elist[pos] = e;
        }
    }
}

// ---------------------------------------------------------------------------
// One wave per matched edge: agg[slot] += A_vals[e] * embed[A_cols[e]]
__global__ __launch_bounds__(256) void agg_kernel(
    const int* __restrict__ elist, const int* __restrict__ counter,
    const int* __restrict__ A_rows, const int* __restrict__ A_cols,
    const float* __restrict__ A_vals, const int* __restrict__ map,
    const float* __restrict__ embed, float* __restrict__ agg)
{
    const int lane = threadIdx.x & 63;
    const int gw = (blockIdx.x * blockDim.x + threadIdx.x) >> 6;
    const int nw = (gridDim.x * blockDim.x) >> 6;
    const int cnt = *counter;
    for (int i = gw; i < cnt; i += nw) {
        const int e = elist[i];
        const int r = A_rows[e];
        const int s = map[r];
        const float v = A_vals[e];
        const int c = A_cols[e];
        const float* erow = embed + (size_t)c * D;
        atomicAdd(&agg[(size_t)s * D + lane],      v * erow[lane]);
        atomicAdd(&agg[(size_t)s * D + 64 + lane], v * erow[64 + lane]);
    }
}

// ---------------------------------------------------------------------------
// X[b] = [ embed[row]+agg[slot] (128) | cat_mean + relu(numW@numf + numb) (128) ]
__global__ __launch_bounds__(256) void build_x_kernel(
    const int* __restrict__ ids,
    const int* __restrict__ cat_feats,   // [Nside][8]
    const float* __restrict__ num_feats, // [Nside][16]
    const float* __restrict__ cat_table, // [1001][128]
    const float* __restrict__ numW,      // [128][16]
    const float* __restrict__ numb,      // [128]
    const float* __restrict__ embed,     // [NTOT][128]
    const int* __restrict__ map,
    const float* __restrict__ agg,       // [2B][128]
    float* __restrict__ Xo,              // [B][256]
    int id_offset)
{
    const int tid = threadIdx.x;
    const int lr  = tid >> 7;      // 0..1
    const int d   = tid & 127;
    const int b   = blockIdx.x * 2 + lr;
    const int uid = ids[b];
    const int grow = uid + id_offset;
    const int slot = map[grow];
    const float ev = embed[(size_t)grow * D + d] + agg[(size_t)slot * D + d];

    float csum = 0.f;
    int cnt = 0;
#pragma unroll
    for (int f = 0; f < NCAT; ++f) {
        const int cid = cat_feats[uid * NCAT + f];
        cnt += (cid > 0);
        csum += cat_table[(size_t)cid * D + d];
    }
    const float inv = (cnt > 0) ? (1.0f / (float)cnt) : 0.0f;

    float nacc = numb[d];
#pragma unroll
    for (int k = 0; k < NNUM; ++k)
        nacc += numW[d * NNUM + k] * num_feats[(size_t)uid * NNUM + k];

    const float feat = csum * inv + fmaxf(nacc, 0.0f);
    Xo[(size_t)b * 256 + d]       = ev;
    Xo[(size_t)b * 256 + 128 + d] = feat;
}

// ---------------------------------------------------------------------------
// H = relu(X @ Weff.T + beff).  X:[B][256], Weff:[256][256] row-major, H:[B][256]
// Block: 256 threads, tile 32 rows x 128 cols (grid.y = col half).
// X tile staged k-major in LDS (reads are wave-uniform broadcasts);
// W staged in k-panels of 32, transposed to [kk][j].
#define TM 32
#define KK 32
__global__ __launch_bounds__(256) void linear_relu_kernel(
    const float* __restrict__ Xg, const float* __restrict__ Wg,
    const float* __restrict__ bg, float* __restrict__ Hg)
{
    __shared__ __align__(16) float Xs[256][36];   // [k][r], padded for float4 align
    __shared__ __align__(16) float Ws[KK][132];   // [kk][j], j in [0,128)
    const int tid  = threadIdx.x;
    const int b0   = blockIdx.x * TM;
    const int cb   = blockIdx.y;       // col half: 0 or 1
    const int colg = tid & 63;         // 0..63
    const int rowg = tid >> 6;         // 0..3 (== wave index)
    const int r0   = rowg * 8;
    const int jloc = colg * 2;

    // stage X transposed: Xs[k][r] <- Xg[(b0+r)*256 + k]
    {
        const float* src = Xg + (size_t)b0 * 256 + tid;
#pragma unroll
        for (int r = 0; r < TM; ++r)
            Xs[tid][r] = src[(size_t)r * 256];
    }

    float acc[8][2];
#pragma unroll
    for (int i = 0; i < 8; ++i) { acc[i][0] = 0.f; acc[i][1] = 0.f; }

    for (int kt = 0; kt < 256; kt += KK) {
        __syncthreads();   // X ready (1st iter) / previous compute done
        {
            const int kk = tid & 31;
            const int j0 = tid >> 5;   // 0..7
#pragma unroll
            for (int jj = 0; jj < 128; jj += 8)
                Ws[kk][j0 + jj] = Wg[(size_t)(cb * 128 + j0 + jj) * 256 + kt + kk];
        }
        __syncthreads();
#pragma unroll 4
        for (int kk = 0; kk < KK; ++kk) {
            const int k = kt + kk;
            const float4 xa = *(const float4*)&Xs[k][r0];
            const float4 xb = *(const float4*)&Xs[k][r0 + 4];
            const float2 w  = *(const float2*)&Ws[kk][jloc];
            acc[0][0] += xa.x * w.x; acc[0][1] += xa.x * w.y;
            acc[1][0] += xa.y * w.x; acc[1][1] += xa.y * w.y;
            acc[2][0] += xa.z * w.x; acc[2][1] += xa.z * w.y;
            acc[3][0] += xa.w * w.x; acc[3][1] += xa.w * w.y;
            acc[4][0] += xb.x * w.x; acc[4][1] += xb.x * w.y;
            acc[5][0] += xb.y * w.x; acc[5][1] += xb.y * w.y;
            acc[6][0] += xb.z * w.x; acc[6][1] += xb.z * w.y;
            acc[7][0] += xb.w * w.x; acc[7][1] += xb.w * w.y;
        }
    }

    const int jglob = cb * 128 + jloc;
    const float bia0 = bg[jglob], bia1 = bg[jglob + 1];
#pragma unroll
    for (int i = 0; i < 8; ++i) {
        const int r = b0 + r0 + i;
        float2 h;
        h.x = fmaxf(acc[i][0] + bia0, 0.0f);
        h.y = fmaxf(acc[i][1] + bia1, 0.0f);
        *(float2*)&Hg[(size_t)r * 256 + jglob] = h;
    }
}

// ---------------------------------------------------------------------------
// w[b] = sigmoid( H1[b,:] . w2eff[task,:] + b2eff[task] )  -- one wave per row
__global__ __launch_bounds__(256) void gate_kernel(
    const float* __restrict__ H1, const float* __restrict__ w2eff,
    const float* __restrict__ b2eff, float* __restrict__ wout, int task)
{
    const int tid = threadIdx.x;
    const int wv = tid >> 6, lane = tid & 63;
    const int b = blockIdx.x * 4 + wv;
    const float* h  = H1 + (size_t)b * 256;
    const float* w2 = w2eff + task * 256;
    float s = 0.f;
#pragma unroll
    for (int q = 0; q < 4; ++q) s += h[q * 64 + lane] * w2[q * 64 + lane];
#pragma unroll
    for (int off = 32; off > 0; off >>= 1) s += __shfl_xor(s, off, 64);
    if (lane == 0) wout[b] = 1.0f / (1.0f + expf(-(s + b2eff[task])));
}

// ---------------------------------------------------------------------------
// out[b] = sum_d (wu*eu + (1-wu)*fu) * (wi*ei + (1-wi)*fi)   -- one wave per row
__global__ __launch_bounds__(256) void dot_kernel(
    const float* __restrict__ Xu, const float* __restrict__ Xi,
    const float* __restrict__ wu, const float* __restrict__ wi,
    float* __restrict__ out)
{
    const int tid = threadIdx.x;
    const int wv = tid >> 6, lane = tid & 63;
    const int b = blockIdx.x * 4 + wv;
    const float a = wu[b], c = wi[b];
    const float* xu = Xu + (size_t)b * 256;
    const float* xi = Xi + (size_t)b * 256;
    float s = 0.f;
#pragma unroll
    for (int q = 0; q < 2; ++q) {
        const int d = q * 64 + lane;
        const float u = a * xu[d] + (1.f - a) * xu[128 + d];
        const float v = c * xi[d] + (1.f - c) * xi[128 + d];
        s += u * v;
    }
#pragma unroll
    for (int off = 32; off > 0; off >>= 1) s += __shfl_xor(s, off, 64);
    if (lane == 0) out[b] = s;
}

// ---------------------------------------------------------------------------
extern "C" void kernel_launch(void* const* d_in, const int* in_sizes, int n_in,
                              void* d_out, int out_size, void* d_ws, size_t ws_size,
                              hipStream_t stream)
{
    const float* embed    = (const float*)d_in[0];
    const float* A_vals   = (const float*)d_in[1];
    const float* u_cat_tab= (const float*)d_in[2];
    const float* i_cat_tab= (const float*)d_in[3];
    const float* numW_u   = (const float*)d_in[4];
    const float* numb_u   = (const float*)d_in[5];
    const float* numW_i   = (const float*)d_in[6];
    const float* numb_i   = (const float*)d_in[7];
    const float* W0  = (const float*)d_in[8];
    const float* b0  = (const float*)d_in[9];
    const float* Mw0 = (const float*)d_in[10];
    const float* Mb0 = (const float*)d_in[11];
    const float* W1  = (const float*)d_in[12];
    const float* b1  = (const float*)d_in[13];
    const float* Mw1 = (const float*)d_in[14];
    const float* Mb1 = (const float*)d_in[15];
    const float* W2  = (const float*)d_in[16];
    const float* b2  = (const float*)d_in[17];
    const float* Mw2 = (const float*)d_in[18];
    const float* Mb2 = (const float*)d_in[19];
    const float* u_numf = (const float*)d_in[20];
    const float* i_numf = (const float*)d_in[21];
    const int* A_rows = (const int*)d_in[22];
    const int* A_cols = (const int*)d_in[23];
    const int* u_catf = (const int*)d_in[24];
    const int* i_catf = (const int*)d_in[25];
    const int* u_ids  = (const int*)d_in[26];
    const int* i_ids  = (const int*)d_in[27];
    float* out = (float*)d_out;

    char* ws = (char*)d_ws;
    size_t off = 0;
    auto alloc = [&](size_t bytes) -> void* {
        void* p = ws + off;
        off += (bytes + 255) & ~(size_t)255;
        return p;
    };
    int*   map     = (int*)  alloc((size_t)NTOT * 4);
    int*   counter = (int*)  alloc(4);
    int*   elist   = (int*)  alloc((size_t)E_EDGES * 4);
    float* agg     = (float*)alloc((size_t)2 * B * D * 4);
    float* Weff0   = (float*)alloc((size_t)2 * 65536 * 4);
    float* Weff1   = (float*)alloc((size_t)2 * 65536 * 4);
    float* w2eff   = (float*)alloc(512 * 4);
    float* beff0   = (float*)alloc(512 * 4);
    float* beff1   = (float*)alloc(512 * 4);
    float* b2eff   = (float*)alloc(2 * 4);
    float* Xu      = (float*)alloc((size_t)B * 256 * 4);
    float* Xi      = (float*)alloc((size_t)B * 256 * 4);
    float* H0      = (float*)alloc((size_t)B * 256 * 4);
    float* H1      = (float*)alloc((size_t)B * 256 * 4);
    float* w_u     = (float*)alloc((size_t)B * 4);
    float* w_i     = (float*)alloc((size_t)B * 4);

    hipMemsetAsync(map, 0xFF, (size_t)NTOT * 4, stream);        // -1
    hipMemsetAsync(counter, 0, 4, stream);
    hipMemsetAsync(agg, 0, (size_t)2 * B * D * 4, stream);

    build_map_kernel<<<(B + 255) / 256, 256, 0, stream>>>(u_ids, i_ids, map);
    weff_kernel<<<(263682 + 255) / 256, 256, 0, stream>>>(
        W0, Mw0, b0, Mb0, W1, Mw1, b1, Mb1, W2, Mw2, b2, Mb2,
        Weff0, Weff1, w2eff, beff0, beff1, b2eff);
    filter_kernel<<<(E_EDGES + 255) / 256, 256, 0, stream>>>(A_rows, map, counter, elist);
    agg_kernel<<<1024, 256, 0, stream>>>(elist, counter, A_rows, A_cols, A_vals, map, embed, agg);

    build_x_kernel<<<B / 2, 256, 0, stream>>>(u_ids, u_catf, u_numf, u_cat_tab,
                                              numW_u, numb_u, embed, map, agg, Xu, N_ENT);
    build_x_kernel<<<B / 2, 256, 0, stream>>>(i_ids, i_catf, i_numf, i_cat_tab,
                                              numW_i, numb_i, embed, map, agg, Xi, 0);

    dim3 ggrid(B / TM, 2);
    // user side: task 0
    linear_relu_kernel<<<ggrid, 256, 0, stream>>>(Xu, Weff0,         beff0,       H0);
    linear_relu_kernel<<<ggrid, 256, 0, stream>>>(H0, Weff1,         beff1,       H1);
    gate_kernel<<<B / 4, 256, 0, stream>>>(H1, w2eff, b2eff, w_u, 0);
    // item side: task 1
    linear_relu_kernel<<<ggrid, 256, 0, stream>>>(Xi, Weff0 + 65536, beff0 + 256, H0);
    linear_relu_kernel<<<ggrid, 256, 0, stream>>>(H0, Weff1 + 65536, beff1 + 256, H1);
    gate_kernel<<<B / 4, 256, 0, stream>>>(H1, w2eff, b2eff, w_i, 1);

    dot_kernel<<<B / 4, 256, 0, stream>>>(Xu, Xi, w_u, w_i, out);
}

// Round 2
// 219.021 us; speedup vs baseline: 2.5780x; 2.5780x over previous
//
#include <hip/hip_runtime.h>
#include <math.h>

#define N_USERS 50000
#define N_ENT   200000
#define NTOT    250000
#define D       128
#define E_EDGES 2000000
#define B       8192
#define NCAT    8
#define NNUM    16
#define HDIM    256   // 2*D

__device__ __forceinline__ float sigf(float x) { return 1.0f / (1.0f + expf(-x)); }

// ---------------------------------------------------------------------------
// Build row -> slot map. Users occupy global rows [N_ENT, NTOT), slots [0,B).
// Items occupy rows [0, N_ENT), slots [B, 2B). Duplicates dedup via atomicMax.
__global__ __launch_bounds__(256) void build_map_kernel(
    const int* __restrict__ uids, const int* __restrict__ iids, int* __restrict__ map)
{
    int b = blockIdx.x * 256 + threadIdx.x;
    if (b < B) {
        atomicMax(&map[uids[b] + N_ENT], b);
        atomicMax(&map[iids[b]], B + b);
    }
}

// ---------------------------------------------------------------------------
// Effective (masked) weights: Weff = W * sigmoid(Mw[task]), beff = b * sigmoid(Mb[task])
__global__ __launch_bounds__(256) void weff_kernel(
    const float* __restrict__ W0, const float* __restrict__ Mw0,
    const float* __restrict__ b0, const float* __restrict__ Mb0,
    const float* __restrict__ W1, const float* __restrict__ Mw1,
    const float* __restrict__ b1, const float* __restrict__ Mb1,
    const float* __restrict__ W2, const float* __restrict__ Mw2,
    const float* __restrict__ b2, const float* __restrict__ Mb2,
    float* __restrict__ Weff0, float* __restrict__ Weff1, float* __restrict__ w2eff,
    float* __restrict__ beff0, float* __restrict__ beff1, float* __restrict__ b2eff)
{
    int i = blockIdx.x * 256 + threadIdx.x;
    if (i < 131072) {                     // Weff0: [2][256][256]
        int rem = i & 65535;
        Weff0[i] = W0[rem] * sigf(Mw0[i]);
    } else if (i < 262144) {              // Weff1
        int ii = i - 131072;
        int rem = ii & 65535;
        Weff1[ii] = W1[rem] * sigf(Mw1[ii]);
    } else if (i < 262656) {              // w2eff: [2][256]
        int ii = i - 262144;
        int j = ii & 255;
        w2eff[ii] = W2[j] * sigf(Mw2[ii]);
    } else if (i < 263168) {              // beff0: [2][256]
        int ii = i - 262656;
        int j = ii & 255;
        beff0[ii] = b0[j] * sigf(Mb0[ii]);
    } else if (i < 263680) {              // beff1
        int ii = i - 263168;
        int j = ii & 255;
        beff1[ii] = b1[j] * sigf(Mb1[ii]);
    } else if (i < 263682) {              // b2eff: [2]
        int ii = i - 263680;
        b2eff[ii] = b2[0] * sigf(Mb2[ii]);
    }
}

// ---------------------------------------------------------------------------
// Fused filter + aggregate. Each wave takes 64 consecutive edges, ballots the
// ones whose destination row is in the batch (~6%), then cooperatively
// accumulates v * embed[col] into the agg slot for each matched edge.
// No single-address atomics anywhere.
__global__ __launch_bounds__(256) void edge_agg_kernel(
    const int* __restrict__ A_rows, const int* __restrict__ A_cols,
    const float* __restrict__ A_vals, const int* __restrict__ map,
    const float* __restrict__ embed, float* __restrict__ agg)
{
    const int lane = threadIdx.x & 63;
    const int gw = (blockIdx.x * blockDim.x + threadIdx.x) >> 6;
    const int nw = (gridDim.x * blockDim.x) >> 6;
    for (int base = gw * 64; base < E_EDGES; base += nw * 64) {
        const int e = base + lane;
        int slot = -1, col = 0;
        float val = 0.f;
        if (e < E_EDGES) {
            slot = map[A_rows[e]];
            if (slot >= 0) { col = A_cols[e]; val = A_vals[e]; }
        }
        unsigned long long m = __ballot(slot >= 0);
        while (m) {
            const int src = __ffsll(m) - 1;
            m &= m - 1;
            const int   s = __shfl(slot, src);
            const int   c = __shfl(col,  src);
            const float v = __shfl(val,  src);
            const float* erow = embed + (size_t)c * D;
            atomicAdd(&agg[(size_t)s * D + lane],      v * erow[lane]);
            atomicAdd(&agg[(size_t)s * D + 64 + lane], v * erow[64 + lane]);
        }
    }
}

// ---------------------------------------------------------------------------
// X[b] = [ embed[row]+agg[slot] (128) | cat_mean + relu(numW@numf + numb) (128) ]
__global__ __launch_bounds__(256) void build_x_kernel(
    const int* __restrict__ ids,
    const int* __restrict__ cat_feats,   // [Nside][8]
    const float* __restrict__ num_feats, // [Nside][16]
    const float* __restrict__ cat_table, // [1001][128]
    const float* __restrict__ numW,      // [128][16]
    const float* __restrict__ numb,      // [128]
    const float* __restrict__ embed,     // [NTOT][128]
    const int* __restrict__ map,
    const float* __restrict__ agg,       // [2B][128]
    float* __restrict__ Xo,              // [B][256]
    int id_offset)
{
    const int tid = threadIdx.x;
    const int lr  = tid >> 7;      // 0..1
    const int d   = tid & 127;
    const int b   = blockIdx.x * 2 + lr;
    const int uid = ids[b];
    const int grow = uid + id_offset;
    const int slot = map[grow];
    const float ev = embed[(size_t)grow * D + d] + agg[(size_t)slot * D + d];

    float csum = 0.f;
    int cnt = 0;
#pragma unroll
    for (int f = 0; f < NCAT; ++f) {
        const int cid = cat_feats[uid * NCAT + f];
        cnt += (cid > 0);
        csum += cat_table[(size_t)cid * D + d];
    }
    const float inv = (cnt > 0) ? (1.0f / (float)cnt) : 0.0f;

    float nacc = numb[d];
#pragma unroll
    for (int k = 0; k < NNUM; ++k)
        nacc += numW[d * NNUM + k] * num_feats[(size_t)uid * NNUM + k];

    const float feat = csum * inv + fmaxf(nacc, 0.0f);
    Xo[(size_t)b * 256 + d]       = ev;
    Xo[(size_t)b * 256 + 128 + d] = feat;
}

// ---------------------------------------------------------------------------
// H = relu(X @ Weff.T + beff).  X:[B][256], Weff:[256][256] row-major, H:[B][256]
// Block: 256 threads, tile 32 rows x 128 cols (grid.y = col half).
// X tile staged k-major in LDS (reads are wave-uniform broadcasts);
// W staged in k-panels of 32, transposed to [kk][j].
#define TM 32
#define KK 32
__global__ __launch_bounds__(256) void linear_relu_kernel(
    const float* __restrict__ Xg, const float* __restrict__ Wg,
    const float* __restrict__ bg, float* __restrict__ Hg)
{
    __shared__ __align__(16) float Xs[256][36];   // [k][r], padded for float4 align
    __shared__ __align__(16) float Ws[KK][132];   // [kk][j], j in [0,128)
    const int tid  = threadIdx.x;
    const int b0   = blockIdx.x * TM;
    const int cb   = blockIdx.y;       // col half: 0 or 1
    const int colg = tid & 63;         // 0..63
    const int rowg = tid >> 6;         // 0..3 (== wave index)
    const int r0   = rowg * 8;
    const int jloc = colg * 2;

    // stage X transposed: Xs[k][r] <- Xg[(b0+r)*256 + k]
    {
        const float* src = Xg + (size_t)b0 * 256 + tid;
#pragma unroll
        for (int r = 0; r < TM; ++r)
            Xs[tid][r] = src[(size_t)r * 256];
    }

    float acc[8][2];
#pragma unroll
    for (int i = 0; i < 8; ++i) { acc[i][0] = 0.f; acc[i][1] = 0.f; }

    for (int kt = 0; kt < 256; kt += KK) {
        __syncthreads();   // X ready (1st iter) / previous compute done
        {
            const int kk = tid & 31;
            const int j0 = tid >> 5;   // 0..7
#pragma unroll
            for (int jj = 0; jj < 128; jj += 8)
                Ws[kk][j0 + jj] = Wg[(size_t)(cb * 128 + j0 + jj) * 256 + kt + kk];
        }
        __syncthreads();
#pragma unroll 4
        for (int kk = 0; kk < KK; ++kk) {
            const int k = kt + kk;
            const float4 xa = *(const float4*)&Xs[k][r0];
            const float4 xb = *(const float4*)&Xs[k][r0 + 4];
            const float2 w  = *(const float2*)&Ws[kk][jloc];
            acc[0][0] += xa.x * w.x; acc[0][1] += xa.x * w.y;
            acc[1][0] += xa.y * w.x; acc[1][1] += xa.y * w.y;
            acc[2][0] += xa.z * w.x; acc[2][1] += xa.z * w.y;
            acc[3][0] += xa.w * w.x; acc[3][1] += xa.w * w.y;
            acc[4][0] += xb.x * w.x; acc[4][1] += xb.x * w.y;
            acc[5][0] += xb.y * w.x; acc[5][1] += xb.y * w.y;
            acc[6][0] += xb.z * w.x; acc[6][1] += xb.z * w.y;
            acc[7][0] += xb.w * w.x; acc[7][1] += xb.w * w.y;
        }
    }

    const int jglob = cb * 128 + jloc;
    const float bia0 = bg[jglob], bia1 = bg[jglob + 1];
#pragma unroll
    for (int i = 0; i < 8; ++i) {
        const int r = b0 + r0 + i;
        float2 h;
        h.x = fmaxf(acc[i][0] + bia0, 0.0f);
        h.y = fmaxf(acc[i][1] + bia1, 0.0f);
        *(float2*)&Hg[(size_t)r * 256 + jglob] = h;
    }
}

// ---------------------------------------------------------------------------
// w[b] = sigmoid( H1[b,:] . w2eff[task,:] + b2eff[task] )  -- one wave per row
__global__ __launch_bounds__(256) void gate_kernel(
    const float* __restrict__ H1, const float* __restrict__ w2eff,
    const float* __restrict__ b2eff, float* __restrict__ wout, int task)
{
    const int tid = threadIdx.x;
    const int wv = tid >> 6, lane = tid & 63;
    const int b = blockIdx.x * 4 + wv;
    const float* h  = H1 + (size_t)b * 256;
    const float* w2 = w2eff + task * 256;
    float s = 0.f;
#pragma unroll
    for (int q = 0; q < 4; ++q) s += h[q * 64 + lane] * w2[q * 64 + lane];
#pragma unroll
    for (int off = 32; off > 0; off >>= 1) s += __shfl_xor(s, off, 64);
    if (lane == 0) wout[b] = 1.0f / (1.0f + expf(-(s + b2eff[task])));
}

// ---------------------------------------------------------------------------
// out[b] = sum_d (wu*eu + (1-wu)*fu) * (wi*ei + (1-wi)*fi)   -- one wave per row
__global__ __launch_bounds__(256) void dot_kernel(
    const float* __restrict__ Xu, const float* __restrict__ Xi,
    const float* __restrict__ wu, const float* __restrict__ wi,
    float* __restrict__ out)
{
    const int tid = threadIdx.x;
    const int wv = tid >> 6, lane = tid & 63;
    const int b = blockIdx.x * 4 + wv;
    const float a = wu[b], c = wi[b];
    const float* xu = Xu + (size_t)b * 256;
    const float* xi = Xi + (size_t)b * 256;
    float s = 0.f;
#pragma unroll
    for (int q = 0; q < 2; ++q) {
        const int d = q * 64 + lane;
        const float u = a * xu[d] + (1.f - a) * xu[128 + d];
        const float v = c * xi[d] + (1.f - c) * xi[128 + d];
        s += u * v;
    }
#pragma unroll
    for (int off = 32; off > 0; off >>= 1) s += __shfl_xor(s, off, 64);
    if (lane == 0) out[b] = s;
}

// ---------------------------------------------------------------------------
extern "C" void kernel_launch(void* const* d_in, const int* in_sizes, int n_in,
                              void* d_out, int out_size, void* d_ws, size_t ws_size,
                              hipStream_t stream)
{
    const float* embed    = (const float*)d_in[0];
    const float* A_vals   = (const float*)d_in[1];
    const float* u_cat_tab= (const float*)d_in[2];
    const float* i_cat_tab= (const float*)d_in[3];
    const float* numW_u   = (const float*)d_in[4];
    const float* numb_u   = (const float*)d_in[5];
    const float* numW_i   = (const float*)d_in[6];
    const float* numb_i   = (const float*)d_in[7];
    const float* W0  = (const float*)d_in[8];
    const float* b0  = (const float*)d_in[9];
    const float* Mw0 = (const float*)d_in[10];
    const float* Mb0 = (const float*)d_in[11];
    const float* W1  = (const float*)d_in[12];
    const float* b1  = (const float*)d_in[13];
    const float* Mw1 = (const float*)d_in[14];
    const float* Mb1 = (const float*)d_in[15];
    const float* W2  = (const float*)d_in[16];
    const float* b2  = (const float*)d_in[17];
    const float* Mw2 = (const float*)d_in[18];
    const float* Mb2 = (const float*)d_in[19];
    const float* u_numf = (const float*)d_in[20];
    const float* i_numf = (const float*)d_in[21];
    const int* A_rows = (const int*)d_in[22];
    const int* A_cols = (const int*)d_in[23];
    const int* u_catf = (const int*)d_in[24];
    const int* i_catf = (const int*)d_in[25];
    const int* u_ids  = (const int*)d_in[26];
    const int* i_ids  = (const int*)d_in[27];
    float* out = (float*)d_out;

    char* ws = (char*)d_ws;
    size_t off = 0;
    auto alloc = [&](size_t bytes) -> void* {
        void* p = ws + off;
        off += (bytes + 255) & ~(size_t)255;
        return p;
    };
    int*   map     = (int*)  alloc((size_t)NTOT * 4);
    float* agg     = (float*)alloc((size_t)2 * B * D * 4);
    float* Weff0   = (float*)alloc((size_t)2 * 65536 * 4);
    float* Weff1   = (float*)alloc((size_t)2 * 65536 * 4);
    float* w2eff   = (float*)alloc(512 * 4);
    float* beff0   = (float*)alloc(512 * 4);
    float* beff1   = (float*)alloc(512 * 4);
    float* b2eff   = (float*)alloc(2 * 4);
    float* Xu      = (float*)alloc((size_t)B * 256 * 4);
    float* Xi      = (float*)alloc((size_t)B * 256 * 4);
    float* H0      = (float*)alloc((size_t)B * 256 * 4);
    float* H1      = (float*)alloc((size_t)B * 256 * 4);
    float* w_u     = (float*)alloc((size_t)B * 4);
    float* w_i     = (float*)alloc((size_t)B * 4);

    hipMemsetAsync(map, 0xFF, (size_t)NTOT * 4, stream);        // -1
    hipMemsetAsync(agg, 0, (size_t)2 * B * D * 4, stream);

    build_map_kernel<<<(B + 255) / 256, 256, 0, stream>>>(u_ids, i_ids, map);
    weff_kernel<<<(263682 + 255) / 256, 256, 0, stream>>>(
        W0, Mw0, b0, Mb0, W1, Mw1, b1, Mb1, W2, Mw2, b2, Mb2,
        Weff0, Weff1, w2eff, beff0, beff1, b2eff);
    edge_agg_kernel<<<1024, 256, 0, stream>>>(A_rows, A_cols, A_vals, map, embed, agg);

    build_x_kernel<<<B / 2, 256, 0, stream>>>(u_ids, u_catf, u_numf, u_cat_tab,
                                              numW_u, numb_u, embed, map, agg, Xu, N_ENT);
    build_x_kernel<<<B / 2, 256, 0, stream>>>(i_ids, i_catf, i_numf, i_cat_tab,
                                              numW_i, numb_i, embed, map, agg, Xi, 0);

    dim3 ggrid(B / TM, 2);
    // user side: task 0
    linear_relu_kernel<<<ggrid, 256, 0, stream>>>(Xu, Weff0,         beff0,       H0);
    linear_relu_kernel<<<ggrid, 256, 0, stream>>>(H0, Weff1,         beff1,       H1);
    gate_kernel<<<B / 4, 256, 0, stream>>>(H1, w2eff, b2eff, w_u, 0);
    // item side: task 1
    linear_relu_kernel<<<ggrid, 256, 0, stream>>>(Xi, Weff0 + 65536, beff0 + 256, H0);
    linear_relu_kernel<<<ggrid, 256, 0, stream>>>(H0, Weff1 + 65536, beff1 + 256, H1);
    gate_kernel<<<B / 4, 256, 0, stream>>>(H1, w2eff, b2eff, w_i, 1);

    dot_kernel<<<B / 4, 256, 0, stream>>>(Xu, Xi, w_u, w_i, out);
}

// Round 3
// 179.422 us; speedup vs baseline: 3.1470x; 1.2207x over previous
//
#include <hip/hip_runtime.h>
#include <math.h>

#define N_USERS 50000
#define N_ENT   200000
#define NTOT    250000
#define D       128
#define E_EDGES 2000000
#define B       8192
#define NCAT    8
#define NNUM    16
#define HDIM    256   // 2*D
#define CAP     64    // per-slot edge bin capacity (Poisson(8) degree; overflow ~1e-40)

__device__ __forceinline__ float sigf(float x) { return 1.0f / (1.0f + expf(-x)); }

// ---------------------------------------------------------------------------
// Build row -> slot map. Users occupy global rows [N_ENT, NTOT), slots [0,B).
// Items occupy rows [0, N_ENT), slots [B, 2B). Duplicates dedup via atomicMax.
__global__ __launch_bounds__(256) void build_map_kernel(
    const int* __restrict__ uids, const int* __restrict__ iids, int* __restrict__ map)
{
    int b = blockIdx.x * 256 + threadIdx.x;
    if (b < B) {
        atomicMax(&map[uids[b] + N_ENT], b);
        atomicMax(&map[iids[b]], B + b);
    }
}

// ---------------------------------------------------------------------------
// Effective (masked) weights: Weff = W * sigmoid(Mw[task]), beff = b * sigmoid(Mb[task])
__global__ __launch_bounds__(256) void weff_kernel(
    const float* __restrict__ W0, const float* __restrict__ Mw0,
    const float* __restrict__ b0, const float* __restrict__ Mb0,
    const float* __restrict__ W1, const float* __restrict__ Mw1,
    const float* __restrict__ b1, const float* __restrict__ Mb1,
    const float* __restrict__ W2, const float* __restrict__ Mw2,
    const float* __restrict__ b2, const float* __restrict__ Mb2,
    float* __restrict__ Weff0, float* __restrict__ Weff1, float* __restrict__ w2eff,
    float* __restrict__ beff0, float* __restrict__ beff1, float* __restrict__ b2eff)
{
    int i = blockIdx.x * 256 + threadIdx.x;
    if (i < 131072) {                     // Weff0: [2][256][256]
        int rem = i & 65535;
        Weff0[i] = W0[rem] * sigf(Mw0[i]);
    } else if (i < 262144) {              // Weff1
        int ii = i - 131072;
        int rem = ii & 65535;
        Weff1[ii] = W1[rem] * sigf(Mw1[ii]);
    } else if (i < 262656) {              // w2eff: [2][256]
        int ii = i - 262144;
        int j = ii & 255;
        w2eff[ii] = W2[j] * sigf(Mw2[ii]);
    } else if (i < 263168) {              // beff0: [2][256]
        int ii = i - 262656;
        int j = ii & 255;
        beff0[ii] = b0[j] * sigf(Mb0[ii]);
    } else if (i < 263680) {              // beff1
        int ii = i - 263168;
        int j = ii & 255;
        beff1[ii] = b1[j] * sigf(Mb1[ii]);
    } else if (i < 263682) {              // b2eff: [2]
        int ii = i - 263680;
        b2eff[ii] = b2[0] * sigf(Mb2[ii]);
    }
}

// ---------------------------------------------------------------------------
// Pass 1: matched edges drop (col,val) into per-slot bins. Int atomics spread
// over 16K counters; fp-atomic fallback only on (practically impossible) overflow.
__global__ __launch_bounds__(256) void scatter_kernel(
    const int* __restrict__ A_rows, const int* __restrict__ A_cols,
    const float* __restrict__ A_vals, const int* __restrict__ map,
    int* __restrict__ bincnt, int2* __restrict__ bins,
    const float* __restrict__ embed, float* __restrict__ agg)
{
    const int e = blockIdx.x * 256 + threadIdx.x;
    if (e >= E_EDGES) return;
    const int slot = map[A_rows[e]];
    if (slot < 0) return;
    const int pos = atomicAdd(&bincnt[slot], 1);
    if (pos < CAP) {
        bins[(size_t)slot * CAP + pos] = make_int2(A_cols[e], __float_as_int(A_vals[e]));
    } else {
        // overflow fallback: direct atomic accumulate (agg pre-zeroed)
        const float v = A_vals[e];
        const float* erow = embed + (size_t)A_cols[e] * D;
        for (int d = 0; d < D; ++d)
            atomicAdd(&agg[(size_t)slot * D + d], v * erow[d]);
    }
}

// ---------------------------------------------------------------------------
// Pass 2: one wave per slot; register-accumulate sum(v * embed[col]) over the
// slot's bin; single += write into agg (keeps any overflow contributions).
__global__ __launch_bounds__(256) void gather_accum_kernel(
    const int* __restrict__ bincnt, const int2* __restrict__ bins,
    const float* __restrict__ embed, float* __restrict__ agg)
{
    const int lane = threadIdx.x & 63;
    const int slot = (blockIdx.x * 256 + threadIdx.x) >> 6;
    if (slot >= 2 * B) return;
    const int n = min(bincnt[slot], CAP);
    const int2* bl = bins + (size_t)slot * CAP;
    float a0 = 0.f, a1 = 0.f;
    int j = 0;
    for (; j + 1 < n; j += 2) {          // 2-way ILP: both edge rows in flight
        const int2 c0 = bl[j], c1 = bl[j + 1];
        const float v0 = __int_as_float(c0.y), v1 = __int_as_float(c1.y);
        const float* r0 = embed + (size_t)c0.x * D;
        const float* r1 = embed + (size_t)c1.x * D;
        const float e00 = r0[lane], e01 = r0[64 + lane];
        const float e10 = r1[lane], e11 = r1[64 + lane];
        a0 += v0 * e00 + v1 * e10;
        a1 += v0 * e01 + v1 * e11;
    }
    if (j < n) {
        const int2 c0 = bl[j];
        const float v0 = __int_as_float(c0.y);
        const float* r0 = embed + (size_t)c0.x * D;
        a0 += v0 * r0[lane];
        a1 += v0 * r0[64 + lane];
    }
    agg[(size_t)slot * D + lane]      += a0;
    agg[(size_t)slot * D + 64 + lane] += a1;
}

// ---------------------------------------------------------------------------
// X[b] = [ embed[row]+agg[slot] (128) | cat_mean + relu(numW@numf + numb) (128) ]
__global__ __launch_bounds__(256) void build_x_kernel(
    const int* __restrict__ ids,
    const int* __restrict__ cat_feats,   // [Nside][8]
    const float* __restrict__ num_feats, // [Nside][16]
    const float* __restrict__ cat_table, // [1001][128]
    const float* __restrict__ numW,      // [128][16]
    const float* __restrict__ numb,      // [128]
    const float* __restrict__ embed,     // [NTOT][128]
    const int* __restrict__ map,
    const float* __restrict__ agg,       // [2B][128]
    float* __restrict__ Xo,              // [B][256]
    int id_offset)
{
    const int tid = threadIdx.x;
    const int lr  = tid >> 7;      // 0..1
    const int d   = tid & 127;
    const int b   = blockIdx.x * 2 + lr;
    const int uid = ids[b];
    const int grow = uid + id_offset;
    const int slot = map[grow];
    const float ev = embed[(size_t)grow * D + d] + agg[(size_t)slot * D + d];

    float csum = 0.f;
    int cnt = 0;
#pragma unroll
    for (int f = 0; f < NCAT; ++f) {
        const int cid = cat_feats[uid * NCAT + f];
        cnt += (cid > 0);
        csum += cat_table[(size_t)cid * D + d];
    }
    const float inv = (cnt > 0) ? (1.0f / (float)cnt) : 0.0f;

    float nacc = numb[d];
#pragma unroll
    for (int k = 0; k < NNUM; ++k)
        nacc += numW[d * NNUM + k] * num_feats[(size_t)uid * NNUM + k];

    const float feat = csum * inv + fmaxf(nacc, 0.0f);
    Xo[(size_t)b * 256 + d]       = ev;
    Xo[(size_t)b * 256 + 128 + d] = feat;
}

// ---------------------------------------------------------------------------
// H = relu(X @ Weff.T + beff).  X:[B][256], Weff:[256][256] row-major, H:[B][256]
#define TM 32
#define KK 32
__global__ __launch_bounds__(256) void linear_relu_kernel(
    const float* __restrict__ Xg, const float* __restrict__ Wg,
    const float* __restrict__ bg, float* __restrict__ Hg)
{
    __shared__ __align__(16) float Xs[256][36];   // [k][r], padded for float4 align
    __shared__ __align__(16) float Ws[KK][132];   // [kk][j], j in [0,128)
    const int tid  = threadIdx.x;
    const int b0   = blockIdx.x * TM;
    const int cb   = blockIdx.y;       // col half: 0 or 1
    const int colg = tid & 63;         // 0..63
    const int rowg = tid >> 6;         // 0..3 (== wave index)
    const int r0   = rowg * 8;
    const int jloc = colg * 2;

    // stage X transposed: Xs[k][r] <- Xg[(b0+r)*256 + k]
    {
        const float* src = Xg + (size_t)b0 * 256 + tid;
#pragma unroll
        for (int r = 0; r < TM; ++r)
            Xs[tid][r] = src[(size_t)r * 256];
    }

    float acc[8][2];
#pragma unroll
    for (int i = 0; i < 8; ++i) { acc[i][0] = 0.f; acc[i][1] = 0.f; }

    for (int kt = 0; kt < 256; kt += KK) {
        __syncthreads();   // X ready (1st iter) / previous compute done
        {
            const int kk = tid & 31;
            const int j0 = tid >> 5;   // 0..7
#pragma unroll
            for (int jj = 0; jj < 128; jj += 8)
                Ws[kk][j0 + jj] = Wg[(size_t)(cb * 128 + j0 + jj) * 256 + kt + kk];
        }
        __syncthreads();
#pragma unroll 4
        for (int kk = 0; kk < KK; ++kk) {
            const int k = kt + kk;
            const float4 xa = *(const float4*)&Xs[k][r0];
            const float4 xb = *(const float4*)&Xs[k][r0 + 4];
            const float2 w  = *(const float2*)&Ws[kk][jloc];
            acc[0][0] += xa.x * w.x; acc[0][1] += xa.x * w.y;
            acc[1][0] += xa.y * w.x; acc[1][1] += xa.y * w.y;
            acc[2][0] += xa.z * w.x; acc[2][1] += xa.z * w.y;
            acc[3][0] += xa.w * w.x; acc[3][1] += xa.w * w.y;
            acc[4][0] += xb.x * w.x; acc[4][1] += xb.x * w.y;
            acc[5][0] += xb.y * w.x; acc[5][1] += xb.y * w.y;
            acc[6][0] += xb.z * w.x; acc[6][1] += xb.z * w.y;
            acc[7][0] += xb.w * w.x; acc[7][1] += xb.w * w.y;
        }
    }

    const int jglob = cb * 128 + jloc;
    const float bia0 = bg[jglob], bia1 = bg[jglob + 1];
#pragma unroll
    for (int i = 0; i < 8; ++i) {
        const int r = b0 + r0 + i;
        float2 h;
        h.x = fmaxf(acc[i][0] + bia0, 0.0f);
        h.y = fmaxf(acc[i][1] + bia1, 0.0f);
        *(float2*)&Hg[(size_t)r * 256 + jglob] = h;
    }
}

// ---------------------------------------------------------------------------
// w[b] = sigmoid( H1[b,:] . w2eff[task,:] + b2eff[task] )  -- one wave per row
__global__ __launch_bounds__(256) void gate_kernel(
    const float* __restrict__ H1, const float* __restrict__ w2eff,
    const float* __restrict__ b2eff, float* __restrict__ wout, int task)
{
    const int tid = threadIdx.x;
    const int wv = tid >> 6, lane = tid & 63;
    const int b = blockIdx.x * 4 + wv;
    const float* h  = H1 + (size_t)b * 256;
    const float* w2 = w2eff + task * 256;
    float s = 0.f;
#pragma unroll
    for (int q = 0; q < 4; ++q) s += h[q * 64 + lane] * w2[q * 64 + lane];
#pragma unroll
    for (int off = 32; off > 0; off >>= 1) s += __shfl_xor(s, off, 64);
    if (lane == 0) wout[b] = 1.0f / (1.0f + expf(-(s + b2eff[task])));
}

// ---------------------------------------------------------------------------
// out[b] = sum_d (wu*eu + (1-wu)*fu) * (wi*ei + (1-wi)*fi)   -- one wave per row
__global__ __launch_bounds__(256) void dot_kernel(
    const float* __restrict__ Xu, const float* __restrict__ Xi,
    const float* __restrict__ wu, const float* __restrict__ wi,
    float* __restrict__ out)
{
    const int tid = threadIdx.x;
    const int wv = tid >> 6, lane = tid & 63;
    const int b = blockIdx.x * 4 + wv;
    const float a = wu[b], c = wi[b];
    const float* xu = Xu + (size_t)b * 256;
    const float* xi = Xi + (size_t)b * 256;
    float s = 0.f;
#pragma unroll
    for (int q = 0; q < 2; ++q) {
        const int d = q * 64 + lane;
        const float u = a * xu[d] + (1.f - a) * xu[128 + d];
        const float v = c * xi[d] + (1.f - c) * xi[128 + d];
        s += u * v;
    }
#pragma unroll
    for (int off = 32; off > 0; off >>= 1) s += __shfl_xor(s, off, 64);
    if (lane == 0) out[b] = s;
}

// ---------------------------------------------------------------------------
extern "C" void kernel_launch(void* const* d_in, const int* in_sizes, int n_in,
                              void* d_out, int out_size, void* d_ws, size_t ws_size,
                              hipStream_t stream)
{
    const float* embed    = (const float*)d_in[0];
    const float* A_vals   = (const float*)d_in[1];
    const float* u_cat_tab= (const float*)d_in[2];
    const float* i_cat_tab= (const float*)d_in[3];
    const float* numW_u   = (const float*)d_in[4];
    const float* numb_u   = (const float*)d_in[5];
    const float* numW_i   = (const float*)d_in[6];
    const float* numb_i   = (const float*)d_in[7];
    const float* W0  = (const float*)d_in[8];
    const float* b0  = (const float*)d_in[9];
    const float* Mw0 = (const float*)d_in[10];
    const float* Mb0 = (const float*)d_in[11];
    const float* W1  = (const float*)d_in[12];
    const float* b1  = (const float*)d_in[13];
    const float* Mw1 = (const float*)d_in[14];
    const float* Mb1 = (const float*)d_in[15];
    const float* W2  = (const float*)d_in[16];
    const float* b2  = (const float*)d_in[17];
    const float* Mw2 = (const float*)d_in[18];
    const float* Mb2 = (const float*)d_in[19];
    const float* u_numf = (const float*)d_in[20];
    const float* i_numf = (const float*)d_in[21];
    const int* A_rows = (const int*)d_in[22];
    const int* A_cols = (const int*)d_in[23];
    const int* u_catf = (const int*)d_in[24];
    const int* i_catf = (const int*)d_in[25];
    const int* u_ids  = (const int*)d_in[26];
    const int* i_ids  = (const int*)d_in[27];
    float* out = (float*)d_out;

    char* ws = (char*)d_ws;
    size_t off = 0;
    auto alloc = [&](size_t bytes) -> void* {
        void* p = ws + off;
        off += (bytes + 255) & ~(size_t)255;
        return p;
    };
    int*   map     = (int*)  alloc((size_t)NTOT * 4);
    float* agg     = (float*)alloc((size_t)2 * B * D * 4);
    int*   bincnt  = (int*)  alloc((size_t)2 * B * 4);
    int2*  bins    = (int2*) alloc((size_t)2 * B * CAP * 8);
    float* Weff0   = (float*)alloc((size_t)2 * 65536 * 4);
    float* Weff1   = (float*)alloc((size_t)2 * 65536 * 4);
    float* w2eff   = (float*)alloc(512 * 4);
    float* beff0   = (float*)alloc(512 * 4);
    float* beff1   = (float*)alloc(512 * 4);
    float* b2eff   = (float*)alloc(2 * 4);
    float* Xu      = (float*)alloc((size_t)B * 256 * 4);
    float* Xi      = (float*)alloc((size_t)B * 256 * 4);
    float* H0      = (float*)alloc((size_t)B * 256 * 4);
    float* H1      = (float*)alloc((size_t)B * 256 * 4);
    float* w_u     = (float*)alloc((size_t)B * 4);
    float* w_i     = (float*)alloc((size_t)B * 4);

    hipMemsetAsync(map, 0xFF, (size_t)NTOT * 4, stream);        // -1
    hipMemsetAsync(agg, 0, (size_t)2 * B * D * 4, stream);
    hipMemsetAsync(bincnt, 0, (size_t)2 * B * 4, stream);

    build_map_kernel<<<(B + 255) / 256, 256, 0, stream>>>(u_ids, i_ids, map);
    weff_kernel<<<(263682 + 255) / 256, 256, 0, stream>>>(
        W0, Mw0, b0, Mb0, W1, Mw1, b1, Mb1, W2, Mw2, b2, Mb2,
        Weff0, Weff1, w2eff, beff0, beff1, b2eff);
    scatter_kernel<<<(E_EDGES + 255) / 256, 256, 0, stream>>>(
        A_rows, A_cols, A_vals, map, bincnt, bins, embed, agg);
    gather_accum_kernel<<<(2 * B * 64) / 256, 256, 0, stream>>>(bincnt, bins, embed, agg);

    build_x_kernel<<<B / 2, 256, 0, stream>>>(u_ids, u_catf, u_numf, u_cat_tab,
                                              numW_u, numb_u, embed, map, agg, Xu, N_ENT);
    build_x_kernel<<<B / 2, 256, 0, stream>>>(i_ids, i_catf, i_numf, i_cat_tab,
                                              numW_i, numb_i, embed, map, agg, Xi, 0);

    dim3 ggrid(B / TM, 2);
    // user side: task 0
    linear_relu_kernel<<<ggrid, 256, 0, stream>>>(Xu, Weff0,         beff0,       H0);
    linear_relu_kernel<<<ggrid, 256, 0, stream>>>(H0, Weff1,         beff1,       H1);
    gate_kernel<<<B / 4, 256, 0, stream>>>(H1, w2eff, b2eff, w_u, 0);
    // item side: task 1
    linear_relu_kernel<<<ggrid, 256, 0, stream>>>(Xi, Weff0 + 65536, beff0 + 256, H0);
    linear_relu_kernel<<<ggrid, 256, 0, stream>>>(H0, Weff1 + 65536, beff1 + 256, H1);
    gate_kernel<<<B / 4, 256, 0, stream>>>(H1, w2eff, b2eff, w_i, 1);

    dot_kernel<<<B / 4, 256, 0, stream>>>(Xu, Xi, w_u, w_i, out);
}

// Round 4
// 97.295 us; speedup vs baseline: 5.8033x; 1.8441x over previous
//
#include <hip/hip_runtime.h>
#include <math.h>

#define N_USERS 50000
#define N_ENT   200000
#define NTOT    250000
#define D       128
#define E_EDGES 2000000
#define B       8192
#define NCAT    8
#define NNUM    16
#define CAP     64    // per-slot edge bin capacity (Poisson(8) degree; overflow ~1e-40)

typedef __attribute__((ext_vector_type(4))) float f32x4;
typedef __attribute__((ext_vector_type(8))) short short8;

__device__ __forceinline__ float sigf(float x) { return 1.0f / (1.0f + expf(-x)); }

// fp32 -> bf16 RNE
__device__ __forceinline__ short f2bf(float f) {
    unsigned u = __float_as_uint(f);
    unsigned r = (u + 0x7FFF + ((u >> 16) & 1)) >> 16;
    return (short)r;
}

// ---------------------------------------------------------------------------
__global__ __launch_bounds__(256) void build_map_kernel(
    const int* __restrict__ uids, const int* __restrict__ iids, int* __restrict__ map)
{
    int b = blockIdx.x * 256 + threadIdx.x;
    if (b < B) {
        atomicMax(&map[uids[b] + N_ENT], b);
        atomicMax(&map[iids[b]], B + b);
    }
}

// ---------------------------------------------------------------------------
// Weffh = bf16(W * sigmoid(Mw[task])), biases fp32.
__global__ __launch_bounds__(256) void weff_kernel(
    const float* __restrict__ W0, const float* __restrict__ Mw0,
    const float* __restrict__ b0, const float* __restrict__ Mb0,
    const float* __restrict__ W1, const float* __restrict__ Mw1,
    const float* __restrict__ b1, const float* __restrict__ Mb1,
    const float* __restrict__ W2, const float* __restrict__ Mw2,
    const float* __restrict__ b2, const float* __restrict__ Mb2,
    short* __restrict__ W0h, short* __restrict__ W1h, float* __restrict__ w2eff,
    float* __restrict__ beff0, float* __restrict__ beff1, float* __restrict__ b2eff)
{
    int i = blockIdx.x * 256 + threadIdx.x;
    if (i < 131072) {                     // W0h: [2][256][256]
        W0h[i] = f2bf(W0[i & 65535] * sigf(Mw0[i]));
    } else if (i < 262144) {              // W1h
        int ii = i - 131072;
        W1h[ii] = f2bf(W1[ii & 65535] * sigf(Mw1[ii]));
    } else if (i < 262656) {              // w2eff: [2][256]
        int ii = i - 262144;
        w2eff[ii] = W2[ii & 255] * sigf(Mw2[ii]);
    } else if (i < 263168) {              // beff0: [2][256]
        int ii = i - 262656;
        beff0[ii] = b0[ii & 255] * sigf(Mb0[ii]);
    } else if (i < 263680) {              // beff1
        int ii = i - 263168;
        beff1[ii] = b1[ii & 255] * sigf(Mb1[ii]);
    } else if (i < 263682) {              // b2eff: [2]
        int ii = i - 263680;
        b2eff[ii] = b2[0] * sigf(Mb2[ii]);
    }
}

// ---------------------------------------------------------------------------
// Pass 1: matched edges drop (col,val) into per-slot bins.
__global__ __launch_bounds__(256) void scatter_kernel(
    const int* __restrict__ A_rows, const int* __restrict__ A_cols,
    const float* __restrict__ A_vals, const int* __restrict__ map,
    int* __restrict__ bincnt, int2* __restrict__ bins,
    const float* __restrict__ embed, float* __restrict__ agg)
{
    const int e = blockIdx.x * 256 + threadIdx.x;
    if (e >= E_EDGES) return;
    const int slot = map[A_rows[e]];
    if (slot < 0) return;
    const int pos = atomicAdd(&bincnt[slot], 1);
    if (pos < CAP) {
        bins[(size_t)slot * CAP + pos] = make_int2(A_cols[e], __float_as_int(A_vals[e]));
    } else {
        const float v = A_vals[e];
        const float* erow = embed + (size_t)A_cols[e] * D;
        for (int d = 0; d < D; ++d)
            atomicAdd(&agg[(size_t)slot * D + d], v * erow[d]);
    }
}

// ---------------------------------------------------------------------------
// Pass 2: one wave per slot; 4-way ILP register accumulate; single += to agg.
__global__ __launch_bounds__(256) void gather_accum_kernel(
    const int* __restrict__ bincnt, const int2* __restrict__ bins,
    const float* __restrict__ embed, float* __restrict__ agg)
{
    const int lane = threadIdx.x & 63;
    const int slot = (blockIdx.x * 256 + threadIdx.x) >> 6;
    if (slot >= 2 * B) return;
    const int n = min(bincnt[slot], CAP);
    const int2* bl = bins + (size_t)slot * CAP;
    float a0 = 0.f, a1 = 0.f;
    int j = 0;
    for (; j + 3 < n; j += 4) {
        const int2 c0 = bl[j], c1 = bl[j + 1], c2 = bl[j + 2], c3 = bl[j + 3];
        const float* r0 = embed + (size_t)c0.x * D;
        const float* r1 = embed + (size_t)c1.x * D;
        const float* r2 = embed + (size_t)c2.x * D;
        const float* r3 = embed + (size_t)c3.x * D;
        const float v0 = __int_as_float(c0.y), v1 = __int_as_float(c1.y);
        const float v2 = __int_as_float(c2.y), v3 = __int_as_float(c3.y);
        a0 += v0 * r0[lane] + v1 * r1[lane] + v2 * r2[lane] + v3 * r3[lane];
        a1 += v0 * r0[64 + lane] + v1 * r1[64 + lane] + v2 * r2[64 + lane] + v3 * r3[64 + lane];
    }
    for (; j < n; ++j) {
        const int2 c0 = bl[j];
        const float v0 = __int_as_float(c0.y);
        const float* r0 = embed + (size_t)c0.x * D;
        a0 += v0 * r0[lane];
        a1 += v0 * r0[64 + lane];
    }
    agg[(size_t)slot * D + lane]      += a0;
    agg[(size_t)slot * D + 64 + lane] += a1;
}

// ---------------------------------------------------------------------------
// X[b] = [ embed[row]+agg[slot] | cat_mean + relu(numW@numf + numb) ]
// grid.y = side (0 user / 1 item)
__global__ __launch_bounds__(256) void build_x_kernel(
    const int* __restrict__ uids, const int* __restrict__ iids,
    const int* __restrict__ u_catf, const int* __restrict__ i_catf,
    const float* __restrict__ u_numf, const float* __restrict__ i_numf,
    const float* __restrict__ u_tab, const float* __restrict__ i_tab,
    const float* __restrict__ numW_u, const float* __restrict__ numb_u,
    const float* __restrict__ numW_i, const float* __restrict__ numb_i,
    const float* __restrict__ embed, const int* __restrict__ map,
    const float* __restrict__ agg,
    float* __restrict__ Xu, float* __restrict__ Xi)
{
    const int side = blockIdx.y;
    const int* ids = side ? iids : uids;
    const int* cat_feats = side ? i_catf : u_catf;
    const float* num_feats = side ? i_numf : u_numf;
    const float* cat_table = side ? i_tab : u_tab;
    const float* numW = side ? numW_i : numW_u;
    const float* numb = side ? numb_i : numb_u;
    float* Xo = side ? Xi : Xu;
    const int id_offset = side ? 0 : N_ENT;

    const int tid = threadIdx.x;
    const int lr  = tid >> 7;
    const int d   = tid & 127;
    const int b   = blockIdx.x * 2 + lr;
    const int uid = ids[b];
    const int grow = uid + id_offset;
    const int slot = map[grow];
    const float ev = embed[(size_t)grow * D + d] + agg[(size_t)slot * D + d];

    float csum = 0.f;
    int cnt = 0;
#pragma unroll
    for (int f = 0; f < NCAT; ++f) {
        const int cid = cat_feats[uid * NCAT + f];
        cnt += (cid > 0);
        csum += cat_table[(size_t)cid * D + d];
    }
    const float inv = (cnt > 0) ? (1.0f / (float)cnt) : 0.0f;

    float nacc = numb[d];
#pragma unroll
    for (int k = 0; k < NNUM; ++k)
        nacc += numW[d * NNUM + k] * num_feats[(size_t)uid * NNUM + k];

    const float feat = csum * inv + fmaxf(nacc, 0.0f);
    Xo[(size_t)b * 256 + d]       = ev;
    Xo[(size_t)b * 256 + 128 + d] = feat;
}

// ---------------------------------------------------------------------------
// Fused MLP: H0 = relu(X@W0^T+b0); H1 = relu(H0@W1^T+b1); w = sigmoid(H1.w2+b2)
// Block: 64 batch rows x 256 cols, 4 waves (wave w owns cols [w*64, w*64+64)).
// X / H0 staged in LDS as bf16, XOR-swizzled (byte ^= (row&7)<<4) so the
// stride-512B fragment reads are 2-way (free) instead of 16-way conflicts.
// MFMA 16x16x32 bf16: A lane l: row=l&15, k=(l>>4)*8+t; B lane l: col=l&15,
// same k; C/D: col=lane&15, row=(lane>>4)*4+reg.
__global__ __launch_bounds__(256) void fused_mlp_kernel(
    const float* __restrict__ Xu, const float* __restrict__ Xi,
    const short* __restrict__ W0h, const short* __restrict__ W1h,  // [2][256][256] bf16
    const float* __restrict__ beff0, const float* __restrict__ beff1,
    const float* __restrict__ w2eff, const float* __restrict__ b2eff,
    float* __restrict__ w_u, float* __restrict__ w_i)
{
    const int side = blockIdx.y;               // == task
    const float* Xg = side ? Xi : Xu;
    float* wout = side ? w_i : w_u;
    const int b0 = blockIdx.x * 64;

    __shared__ __align__(16) short Xs[64 * 256];   // 32KB swizzled bf16
    __shared__ float gsum[4][64];

    const int tid = threadIdx.x;
    const int w   = tid >> 6;
    const int l   = tid & 63;
    const int l15 = l & 15;
    const int l4  = l >> 4;    // 0..3

    // ---- stage X tile (fp32 global -> bf16 LDS, swizzled) ----
#pragma unroll
    for (int i = 0; i < 8; ++i) {
        const int ch  = tid + i * 256;      // 2048 chunks of 8 cols
        const int row = ch >> 5;
        const int c8  = (ch & 31) << 3;
        const float4 f0 = *(const float4*)(Xg + (size_t)(b0 + row) * 256 + c8);
        const float4 f1 = *(const float4*)(Xg + (size_t)(b0 + row) * 256 + c8 + 4);
        short8 hv;
        hv[0] = f2bf(f0.x); hv[1] = f2bf(f0.y); hv[2] = f2bf(f0.z); hv[3] = f2bf(f0.w);
        hv[4] = f2bf(f1.x); hv[5] = f2bf(f1.y); hv[6] = f2bf(f1.z); hv[7] = f2bf(f1.w);
        const int byte = row * 512 + ((c8 * 2) ^ ((row & 7) << 4));
        *(short8*)((char*)Xs + byte) = hv;
    }
    __syncthreads();

    const short* W0l = W0h + (size_t)side * 65536;
    const short* W1l = W1h + (size_t)side * 65536;
    const int cwbase = w * 64;    // wave's col base

    f32x4 acc[4][4];              // [m(row frag)][n(col frag)]
#pragma unroll
    for (int m = 0; m < 4; ++m)
#pragma unroll
        for (int n = 0; n < 4; ++n) acc[m][n] = (f32x4){0.f, 0.f, 0.f, 0.f};

    // ---------------- layer 0 ----------------
#pragma unroll
    for (int ks = 0; ks < 8; ++ks) {
        short8 a[4];
#pragma unroll
        for (int m = 0; m < 4; ++m) {
            const int row = m * 16 + l15;
            const int kb  = ks * 64 + l4 * 16;
            a[m] = *(const short8*)((const char*)Xs + row * 512 + (kb ^ ((row & 7) << 4)));
        }
#pragma unroll
        for (int n = 0; n < 4; ++n) {
            const short8 bb = *(const short8*)(W0l + (size_t)(cwbase + n * 16 + l15) * 256 + ks * 32 + l4 * 8);
            acc[0][n] = __builtin_amdgcn_mfma_f32_16x16x32_bf16(a[0], bb, acc[0][n], 0, 0, 0);
            acc[1][n] = __builtin_amdgcn_mfma_f32_16x16x32_bf16(a[1], bb, acc[1][n], 0, 0, 0);
            acc[2][n] = __builtin_amdgcn_mfma_f32_16x16x32_bf16(a[2], bb, acc[2][n], 0, 0, 0);
            acc[3][n] = __builtin_amdgcn_mfma_f32_16x16x32_bf16(a[3], bb, acc[3][n], 0, 0, 0);
        }
    }
    __syncthreads();   // all layer-0 reads of Xs complete

    // bias + relu, write H0 back into Xs (bf16, same swizzle)
#pragma unroll
    for (int n = 0; n < 4; ++n) {
        const int col = cwbase + n * 16 + l15;
        const float bia = beff0[side * 256 + col];
#pragma unroll
        for (int m = 0; m < 4; ++m)
#pragma unroll
            for (int r = 0; r < 4; ++r) {
                const float v = fmaxf(acc[m][n][r] + bia, 0.f);
                const int row = m * 16 + l4 * 4 + r;
                const int byte = row * 512 + ((col * 2) ^ ((row & 7) << 4));
                *(short*)((char*)Xs + byte) = f2bf(v);
            }
    }
    __syncthreads();

    // ---------------- layer 1 ----------------
#pragma unroll
    for (int m = 0; m < 4; ++m)
#pragma unroll
        for (int n = 0; n < 4; ++n) acc[m][n] = (f32x4){0.f, 0.f, 0.f, 0.f};

#pragma unroll
    for (int ks = 0; ks < 8; ++ks) {
        short8 a[4];
#pragma unroll
        for (int m = 0; m < 4; ++m) {
            const int row = m * 16 + l15;
            const int kb  = ks * 64 + l4 * 16;
            a[m] = *(const short8*)((const char*)Xs + row * 512 + (kb ^ ((row & 7) << 4)));
        }
#pragma unroll
        for (int n = 0; n < 4; ++n) {
            const short8 bb = *(const short8*)(W1l + (size_t)(cwbase + n * 16 + l15) * 256 + ks * 32 + l4 * 8);
            acc[0][n] = __builtin_amdgcn_mfma_f32_16x16x32_bf16(a[0], bb, acc[0][n], 0, 0, 0);
            acc[1][n] = __builtin_amdgcn_mfma_f32_16x16x32_bf16(a[1], bb, acc[1][n], 0, 0, 0);
            acc[2][n] = __builtin_amdgcn_mfma_f32_16x16x32_bf16(a[2], bb, acc[2][n], 0, 0, 0);
            acc[3][n] = __builtin_amdgcn_mfma_f32_16x16x32_bf16(a[3], bb, acc[3][n], 0, 0, 0);
        }
    }

    // ---------------- gate: w = sigmoid( sum_col relu(acc1+b1)*w2 + b2 ) ----
    float w2v[4], b1v[4];
#pragma unroll
    for (int n = 0; n < 4; ++n) {
        const int col = cwbase + n * 16 + l15;
        w2v[n] = w2eff[side * 256 + col];
        b1v[n] = beff1[side * 256 + col];
    }
#pragma unroll
    for (int m = 0; m < 4; ++m)
#pragma unroll
        for (int r = 0; r < 4; ++r) {
            float s = fmaxf(acc[m][0][r] + b1v[0], 0.f) * w2v[0]
                    + fmaxf(acc[m][1][r] + b1v[1], 0.f) * w2v[1]
                    + fmaxf(acc[m][2][r] + b1v[2], 0.f) * w2v[2]
                    + fmaxf(acc[m][3][r] + b1v[3], 0.f) * w2v[3];
            s += __shfl_xor(s, 1, 16);
            s += __shfl_xor(s, 2, 16);
            s += __shfl_xor(s, 4, 16);
            s += __shfl_xor(s, 8, 16);
            if (l15 == 0) gsum[w][m * 16 + l4 * 4 + r] = s;
        }
    __syncthreads();
    if (tid < 64) {
        const float s = gsum[0][tid] + gsum[1][tid] + gsum[2][tid] + gsum[3][tid]
                      + b2eff[side];
        wout[b0 + tid] = 1.0f / (1.0f + expf(-s));
    }
}

// ---------------------------------------------------------------------------
__global__ __launch_bounds__(256) void dot_kernel(
    const float* __restrict__ Xu, const float* __restrict__ Xi,
    const float* __restrict__ wu, const float* __restrict__ wi,
    float* __restrict__ out)
{
    const int tid = threadIdx.x;
    const int wv = tid >> 6, lane = tid & 63;
    const int b = blockIdx.x * 4 + wv;
    const float a = wu[b], c = wi[b];
    const float* xu = Xu + (size_t)b * 256;
    const float* xi = Xi + (size_t)b * 256;
    float s = 0.f;
#pragma unroll
    for (int q = 0; q < 2; ++q) {
        const int d = q * 64 + lane;
        const float u = a * xu[d] + (1.f - a) * xu[128 + d];
        const float v = c * xi[d] + (1.f - c) * xi[128 + d];
        s += u * v;
    }
#pragma unroll
    for (int off = 32; off > 0; off >>= 1) s += __shfl_xor(s, off, 64);
    if (lane == 0) out[b] = s;
}

// ---------------------------------------------------------------------------
extern "C" void kernel_launch(void* const* d_in, const int* in_sizes, int n_in,
                              void* d_out, int out_size, void* d_ws, size_t ws_size,
                              hipStream_t stream)
{
    const float* embed    = (const float*)d_in[0];
    const float* A_vals   = (const float*)d_in[1];
    const float* u_cat_tab= (const float*)d_in[2];
    const float* i_cat_tab= (const float*)d_in[3];
    const float* numW_u   = (const float*)d_in[4];
    const float* numb_u   = (const float*)d_in[5];
    const float* numW_i   = (const float*)d_in[6];
    const float* numb_i   = (const float*)d_in[7];
    const float* W0  = (const float*)d_in[8];
    const float* b0  = (const float*)d_in[9];
    const float* Mw0 = (const float*)d_in[10];
    const float* Mb0 = (const float*)d_in[11];
    const float* W1  = (const float*)d_in[12];
    const float* b1  = (const float*)d_in[13];
    const float* Mw1 = (const float*)d_in[14];
    const float* Mb1 = (const float*)d_in[15];
    const float* W2  = (const float*)d_in[16];
    const float* b2  = (const float*)d_in[17];
    const float* Mw2 = (const float*)d_in[18];
    const float* Mb2 = (const float*)d_in[19];
    const float* u_numf = (const float*)d_in[20];
    const float* i_numf = (const float*)d_in[21];
    const int* A_rows = (const int*)d_in[22];
    const int* A_cols = (const int*)d_in[23];
    const int* u_catf = (const int*)d_in[24];
    const int* i_catf = (const int*)d_in[25];
    const int* u_ids  = (const int*)d_in[26];
    const int* i_ids  = (const int*)d_in[27];
    float* out = (float*)d_out;

    char* ws = (char*)d_ws;
    size_t off = 0;
    auto alloc = [&](size_t bytes) -> void* {
        void* p = ws + off;
        off += (bytes + 255) & ~(size_t)255;
        return p;
    };
    int*   map     = (int*)  alloc((size_t)NTOT * 4);
    float* agg     = (float*)alloc((size_t)2 * B * D * 4);   // agg+bincnt contiguous:
    int*   bincnt  = (int*)  alloc((size_t)2 * B * 4);       // one memset covers both
    int2*  bins    = (int2*) alloc((size_t)2 * B * CAP * 8);
    short* W0h     = (short*)alloc((size_t)2 * 65536 * 2);
    short* W1h     = (short*)alloc((size_t)2 * 65536 * 2);
    float* w2eff   = (float*)alloc(512 * 4);
    float* beff0   = (float*)alloc(512 * 4);
    float* beff1   = (float*)alloc(512 * 4);
    float* b2eff   = (float*)alloc(2 * 4);
    float* Xu      = (float*)alloc((size_t)B * 256 * 4);
    float* Xi      = (float*)alloc((size_t)B * 256 * 4);
    float* w_u     = (float*)alloc((size_t)B * 4);
    float* w_i     = (float*)alloc((size_t)B * 4);

    hipMemsetAsync(map, 0xFF, (size_t)NTOT * 4, stream);                     // -1
    hipMemsetAsync(agg, 0, (size_t)2 * B * D * 4 + (size_t)2 * B * 4, stream); // agg+bincnt

    build_map_kernel<<<(B + 255) / 256, 256, 0, stream>>>(u_ids, i_ids, map);
    weff_kernel<<<(263682 + 255) / 256, 256, 0, stream>>>(
        W0, Mw0, b0, Mb0, W1, Mw1, b1, Mb1, W2, Mw2, b2, Mb2,
        W0h, W1h, w2eff, beff0, beff1, b2eff);
    scatter_kernel<<<(E_EDGES + 255) / 256, 256, 0, stream>>>(
        A_rows, A_cols, A_vals, map, bincnt, bins, embed, agg);
    gather_accum_kernel<<<(2 * B * 64) / 256, 256, 0, stream>>>(bincnt, bins, embed, agg);

    dim3 bxgrid(B / 2, 2);
    build_x_kernel<<<bxgrid, 256, 0, stream>>>(
        u_ids, i_ids, u_catf, i_catf, u_numf, i_numf, u_cat_tab, i_cat_tab,
        numW_u, numb_u, numW_i, numb_i, embed, map, agg, Xu, Xi);

    dim3 mgrid(B / 64, 2);
    fused_mlp_kernel<<<mgrid, 256, 0, stream>>>(
        Xu, Xi, W0h, W1h, beff0, beff1, w2eff, b2eff, w_u, w_i);

    dot_kernel<<<B / 4, 256, 0, stream>>>(Xu, Xi, w_u, w_i, out);
}

// Round 5
// 86.042 us; speedup vs baseline: 6.5624x; 1.1308x over previous
//
#include <hip/hip_runtime.h>
#include <math.h>

#define N_USERS 50000
#define N_ENT   200000
#define NTOT    250000
#define D       128
#define E_EDGES 2000000
#define B       8192
#define NCAT    8
#define NNUM    16
#define CAP     64    // per-slot edge bin capacity (max sampled degree ~30; P(>64)~1e-38)
#define BR      32    // batch rows per MLP block

typedef __attribute__((ext_vector_type(4))) float f32x4;
typedef __attribute__((ext_vector_type(8))) short short8;

__device__ __forceinline__ float sigf(float x) { return 1.0f / (1.0f + expf(-x)); }

// fp32 -> bf16 RNE
__device__ __forceinline__ short f2bf(float f) {
    unsigned u = __float_as_uint(f);
    unsigned r = (u + 0x7FFF + ((u >> 16) & 1)) >> 16;
    return (short)r;
}

// ---------------------------------------------------------------------------
// Fused init: map = -1 (62500 int4), bincnt = 0 (4096 int4), and the masked
// effective weights (bf16 W0h/W1h, fp32 small vectors). One dispatch.
__global__ __launch_bounds__(256) void init_weff_kernel(
    int* __restrict__ map, int* __restrict__ bincnt,
    const float* __restrict__ W0, const float* __restrict__ Mw0,
    const float* __restrict__ b0, const float* __restrict__ Mb0,
    const float* __restrict__ W1, const float* __restrict__ Mw1,
    const float* __restrict__ b1, const float* __restrict__ Mb1,
    const float* __restrict__ W2, const float* __restrict__ Mw2,
    const float* __restrict__ b2, const float* __restrict__ Mb2,
    short* __restrict__ W0h, short* __restrict__ W1h, float* __restrict__ w2eff,
    float* __restrict__ beff0, float* __restrict__ beff1, float* __restrict__ b2eff)
{
    int t = blockIdx.x * 256 + threadIdx.x;
    if (t < 62500) {                       // map: 250000 ints = 62500 int4
        ((int4*)map)[t] = make_int4(-1, -1, -1, -1);
        return;
    }
    t -= 62500;
    if (t < 4096) {                        // bincnt: 16384 ints = 4096 int4
        ((int4*)bincnt)[t] = make_int4(0, 0, 0, 0);
        return;
    }
    int i = t - 4096;                      // weff: 263682 elements
    if (i < 131072) {                      // W0h: [2][256][256]
        W0h[i] = f2bf(W0[i & 65535] * sigf(Mw0[i]));
    } else if (i < 262144) {               // W1h
        int ii = i - 131072;
        W1h[ii] = f2bf(W1[ii & 65535] * sigf(Mw1[ii]));
    } else if (i < 262656) {               // w2eff: [2][256]
        int ii = i - 262144;
        w2eff[ii] = W2[ii & 255] * sigf(Mw2[ii]);
    } else if (i < 263168) {               // beff0: [2][256]
        int ii = i - 262656;
        beff0[ii] = b0[ii & 255] * sigf(Mb0[ii]);
    } else if (i < 263680) {               // beff1
        int ii = i - 263168;
        beff1[ii] = b1[ii & 255] * sigf(Mb1[ii]);
    } else if (i < 263682) {               // b2eff: [2]
        int ii = i - 263680;
        b2eff[ii] = b2[0] * sigf(Mb2[ii]);
    }
}

// ---------------------------------------------------------------------------
// Row -> slot map. Users: global rows [N_ENT,NTOT) -> slots [0,B);
// items: rows [0,N_ENT) -> slots [B,2B). Duplicates dedup via atomicMax.
__global__ __launch_bounds__(256) void build_map_kernel(
    const int* __restrict__ uids, const int* __restrict__ iids, int* __restrict__ map)
{
    int b = blockIdx.x * 256 + threadIdx.x;
    if (b < B) {
        atomicMax(&map[uids[b] + N_ENT], b);
        atomicMax(&map[iids[b]], B + b);
    }
}

// ---------------------------------------------------------------------------
// Matched edges drop (col,val) into their destination slot's bin.
__global__ __launch_bounds__(256) void scatter_kernel(
    const int* __restrict__ A_rows, const int* __restrict__ A_cols,
    const float* __restrict__ A_vals, const int* __restrict__ map,
    int* __restrict__ bincnt, int2* __restrict__ bins)
{
    const int e = blockIdx.x * 256 + threadIdx.x;
    if (e >= E_EDGES) return;
    const int slot = map[A_rows[e]];
    if (slot < 0) return;
    const int pos = atomicAdd(&bincnt[slot], 1);
    if (pos < CAP)
        bins[(size_t)slot * CAP + pos] = make_int2(A_cols[e], __float_as_int(A_vals[e]));
}

// ---------------------------------------------------------------------------
// Fused neighbor-gather + feature build:
// X[b] = [ embed[row] + sum_bin v*embed[col] | cat_mean + relu(numW@numf+numb) ]
// grid = (B/2, 2 sides); 128 threads per row (d = tid&127).
__global__ __launch_bounds__(256) void build_x_kernel(
    const int* __restrict__ uids, const int* __restrict__ iids,
    const int* __restrict__ u_catf, const int* __restrict__ i_catf,
    const float* __restrict__ u_numf, const float* __restrict__ i_numf,
    const float* __restrict__ u_tab, const float* __restrict__ i_tab,
    const float* __restrict__ numW_u, const float* __restrict__ numb_u,
    const float* __restrict__ numW_i, const float* __restrict__ numb_i,
    const float* __restrict__ embed, const int* __restrict__ map,
    const int* __restrict__ bincnt, const int2* __restrict__ bins,
    float* __restrict__ Xu, float* __restrict__ Xi)
{
    const int side = blockIdx.y;
    const int* ids = side ? iids : uids;
    const int* cat_feats = side ? i_catf : u_catf;
    const float* num_feats = side ? i_numf : u_numf;
    const float* cat_table = side ? i_tab : u_tab;
    const float* numW = side ? numW_i : numW_u;
    const float* numb = side ? numb_i : numb_u;
    float* Xo = side ? Xi : Xu;
    const int id_offset = side ? 0 : N_ENT;

    const int tid = threadIdx.x;
    const int lr  = tid >> 7;
    const int d   = tid & 127;
    const int b   = blockIdx.x * 2 + lr;
    const int uid = ids[b];
    const int grow = uid + id_offset;
    const int slot = map[grow];

    float ev = embed[(size_t)grow * D + d];

    // gather this row's neighborhood directly from its bin (replaces agg buffer)
    const int n = min(bincnt[slot], CAP);
    const int2* bl = bins + (size_t)slot * CAP;
    float g0 = 0.f, g1 = 0.f;
    int j = 0;
    for (; j + 1 < n; j += 2) {
        const int2 c0 = bl[j], c1 = bl[j + 1];
        g0 += __int_as_float(c0.y) * embed[(size_t)c0.x * D + d];
        g1 += __int_as_float(c1.y) * embed[(size_t)c1.x * D + d];
    }
    if (j < n) {
        const int2 c0 = bl[j];
        g0 += __int_as_float(c0.y) * embed[(size_t)c0.x * D + d];
    }
    ev += g0 + g1;

    float csum = 0.f;
    int cnt = 0;
#pragma unroll
    for (int f = 0; f < NCAT; ++f) {
        const int cid = cat_feats[uid * NCAT + f];
        cnt += (cid > 0);
        csum += cat_table[(size_t)cid * D + d];
    }
    const float inv = (cnt > 0) ? (1.0f / (float)cnt) : 0.0f;

    float nacc = numb[d];
#pragma unroll
    for (int k = 0; k < NNUM; ++k)
        nacc += numW[d * NNUM + k] * num_feats[(size_t)uid * NNUM + k];

    const float feat = csum * inv + fmaxf(nacc, 0.0f);
    Xo[(size_t)b * 256 + d]       = ev;
    Xo[(size_t)b * 256 + 128 + d] = feat;
}

// ---------------------------------------------------------------------------
// Fused MLP: H0 = relu(X@W0^T+b0); H1 = relu(H0@W1^T+b1); w = sigmoid(H1.w2+b2)
// Block: BR=32 batch rows x 256 cols, 4 waves (wave w owns cols [w*64,w*64+64)).
// X / H0 staged in LDS bf16, XOR-swizzled (byte ^= (row&7)<<4).
// MFMA 16x16x32 bf16 layouts verified in round 4.
__global__ __launch_bounds__(256) void fused_mlp_kernel(
    const float* __restrict__ Xu, const float* __restrict__ Xi,
    const short* __restrict__ W0h, const short* __restrict__ W1h,  // [2][256][256] bf16
    const float* __restrict__ beff0, const float* __restrict__ beff1,
    const float* __restrict__ w2eff, const float* __restrict__ b2eff,
    float* __restrict__ w_u, float* __restrict__ w_i)
{
    const int side = blockIdx.y;               // == task
    const float* Xg = side ? Xi : Xu;
    float* wout = side ? w_i : w_u;
    const int b0 = blockIdx.x * BR;

    __shared__ __align__(16) short Xs[BR * 256];   // 16KB swizzled bf16
    __shared__ float gsum[4][BR];

    const int tid = threadIdx.x;
    const int w   = tid >> 6;
    const int l   = tid & 63;
    const int l15 = l & 15;
    const int l4  = l >> 4;    // 0..3

    // ---- stage X tile (fp32 global -> bf16 LDS, swizzled): 1024 chunks of 8 ----
#pragma unroll
    for (int i = 0; i < 4; ++i) {
        const int ch  = tid + i * 256;
        const int row = ch >> 5;
        const int c8  = (ch & 31) << 3;
        const float4 f0 = *(const float4*)(Xg + (size_t)(b0 + row) * 256 + c8);
        const float4 f1 = *(const float4*)(Xg + (size_t)(b0 + row) * 256 + c8 + 4);
        short8 hv;
        hv[0] = f2bf(f0.x); hv[1] = f2bf(f0.y); hv[2] = f2bf(f0.z); hv[3] = f2bf(f0.w);
        hv[4] = f2bf(f1.x); hv[5] = f2bf(f1.y); hv[6] = f2bf(f1.z); hv[7] = f2bf(f1.w);
        const int byte = row * 512 + ((c8 * 2) ^ ((row & 7) << 4));
        *(short8*)((char*)Xs + byte) = hv;
    }
    __syncthreads();

    const short* W0l = W0h + (size_t)side * 65536;
    const short* W1l = W1h + (size_t)side * 65536;
    const int cwbase = w * 64;    // wave's col base

    f32x4 acc[2][4];              // [m(row frag)][n(col frag)]
#pragma unroll
    for (int m = 0; m < 2; ++m)
#pragma unroll
        for (int n = 0; n < 4; ++n) acc[m][n] = (f32x4){0.f, 0.f, 0.f, 0.f};

    // ---------------- layer 0 ----------------
#pragma unroll
    for (int ks = 0; ks < 8; ++ks) {
        short8 a[2];
#pragma unroll
        for (int m = 0; m < 2; ++m) {
            const int row = m * 16 + l15;
            const int kb  = ks * 64 + l4 * 16;
            a[m] = *(const short8*)((const char*)Xs + row * 512 + (kb ^ ((row & 7) << 4)));
        }
#pragma unroll
        for (int n = 0; n < 4; ++n) {
            const short8 bb = *(const short8*)(W0l + (size_t)(cwbase + n * 16 + l15) * 256 + ks * 32 + l4 * 8);
            acc[0][n] = __builtin_amdgcn_mfma_f32_16x16x32_bf16(a[0], bb, acc[0][n], 0, 0, 0);
            acc[1][n] = __builtin_amdgcn_mfma_f32_16x16x32_bf16(a[1], bb, acc[1][n], 0, 0, 0);
        }
    }
    __syncthreads();   // all layer-0 reads of Xs complete

    // bias + relu, write H0 back into Xs (bf16, same swizzle)
#pragma unroll
    for (int n = 0; n < 4; ++n) {
        const int col = cwbase + n * 16 + l15;
        const float bia = beff0[side * 256 + col];
#pragma unroll
        for (int m = 0; m < 2; ++m)
#pragma unroll
            for (int r = 0; r < 4; ++r) {
                const float v = fmaxf(acc[m][n][r] + bia, 0.f);
                const int row = m * 16 + l4 * 4 + r;
                const int byte = row * 512 + ((col * 2) ^ ((row & 7) << 4));
                *(short*)((char*)Xs + byte) = f2bf(v);
            }
    }
    __syncthreads();

    // ---------------- layer 1 ----------------
#pragma unroll
    for (int m = 0; m < 2; ++m)
#pragma unroll
        for (int n = 0; n < 4; ++n) acc[m][n] = (f32x4){0.f, 0.f, 0.f, 0.f};

#pragma unroll
    for (int ks = 0; ks < 8; ++ks) {
        short8 a[2];
#pragma unroll
        for (int m = 0; m < 2; ++m) {
            const int row = m * 16 + l15;
            const int kb  = ks * 64 + l4 * 16;
            a[m] = *(const short8*)((const char*)Xs + row * 512 + (kb ^ ((row & 7) << 4)));
        }
#pragma unroll
        for (int n = 0; n < 4; ++n) {
            const short8 bb = *(const short8*)(W1l + (size_t)(cwbase + n * 16 + l15) * 256 + ks * 32 + l4 * 8);
            acc[0][n] = __builtin_amdgcn_mfma_f32_16x16x32_bf16(a[0], bb, acc[0][n], 0, 0, 0);
            acc[1][n] = __builtin_amdgcn_mfma_f32_16x16x32_bf16(a[1], bb, acc[1][n], 0, 0, 0);
        }
    }

    // ---------------- gate: w = sigmoid( sum_col relu(acc1+b1)*w2 + b2 ) ----
    float w2v[4], b1v[4];
#pragma unroll
    for (int n = 0; n < 4; ++n) {
        const int col = cwbase + n * 16 + l15;
        w2v[n] = w2eff[side * 256 + col];
        b1v[n] = beff1[side * 256 + col];
    }
#pragma unroll
    for (int m = 0; m < 2; ++m)
#pragma unroll
        for (int r = 0; r < 4; ++r) {
            float s = fmaxf(acc[m][0][r] + b1v[0], 0.f) * w2v[0]
                    + fmaxf(acc[m][1][r] + b1v[1], 0.f) * w2v[1]
                    + fmaxf(acc[m][2][r] + b1v[2], 0.f) * w2v[2]
                    + fmaxf(acc[m][3][r] + b1v[3], 0.f) * w2v[3];
            s += __shfl_xor(s, 1, 16);
            s += __shfl_xor(s, 2, 16);
            s += __shfl_xor(s, 4, 16);
            s += __shfl_xor(s, 8, 16);
            if (l15 == 0) gsum[w][m * 16 + l4 * 4 + r] = s;
        }
    __syncthreads();
    if (tid < BR) {
        const float s = gsum[0][tid] + gsum[1][tid] + gsum[2][tid] + gsum[3][tid]
                      + b2eff[side];
        wout[b0 + tid] = 1.0f / (1.0f + expf(-s));
    }
}

// ---------------------------------------------------------------------------
__global__ __launch_bounds__(256) void dot_kernel(
    const float* __restrict__ Xu, const float* __restrict__ Xi,
    const float* __restrict__ wu, const float* __restrict__ wi,
    float* __restrict__ out)
{
    const int tid = threadIdx.x;
    const int wv = tid >> 6, lane = tid & 63;
    const int b = blockIdx.x * 4 + wv;
    const float a = wu[b], c = wi[b];
    const float* xu = Xu + (size_t)b * 256;
    const float* xi = Xi + (size_t)b * 256;
    float s = 0.f;
#pragma unroll
    for (int q = 0; q < 2; ++q) {
        const int d = q * 64 + lane;
        const float u = a * xu[d] + (1.f - a) * xu[128 + d];
        const float v = c * xi[d] + (1.f - c) * xi[128 + d];
        s += u * v;
    }
#pragma unroll
    for (int off = 32; off > 0; off >>= 1) s += __shfl_xor(s, off, 64);
    if (lane == 0) out[b] = s;
}

// ---------------------------------------------------------------------------
extern "C" void kernel_launch(void* const* d_in, const int* in_sizes, int n_in,
                              void* d_out, int out_size, void* d_ws, size_t ws_size,
                              hipStream_t stream)
{
    const float* embed    = (const float*)d_in[0];
    const float* A_vals   = (const float*)d_in[1];
    const float* u_cat_tab= (const float*)d_in[2];
    const float* i_cat_tab= (const float*)d_in[3];
    const float* numW_u   = (const float*)d_in[4];
    const float* numb_u   = (const float*)d_in[5];
    const float* numW_i   = (const float*)d_in[6];
    const float* numb_i   = (const float*)d_in[7];
    const float* W0  = (const float*)d_in[8];
    const float* b0  = (const float*)d_in[9];
    const float* Mw0 = (const float*)d_in[10];
    const float* Mb0 = (const float*)d_in[11];
    const float* W1  = (const float*)d_in[12];
    const float* b1  = (const float*)d_in[13];
    const float* Mw1 = (const float*)d_in[14];
    const float* Mb1 = (const float*)d_in[15];
    const float* W2  = (const float*)d_in[16];
    const float* b2  = (const float*)d_in[17];
    const float* Mw2 = (const float*)d_in[18];
    const float* Mb2 = (const float*)d_in[19];
    const float* u_numf = (const float*)d_in[20];
    const float* i_numf = (const float*)d_in[21];
    const int* A_rows = (const int*)d_in[22];
    const int* A_cols = (const int*)d_in[23];
    const int* u_catf = (const int*)d_in[24];
    const int* i_catf = (const int*)d_in[25];
    const int* u_ids  = (const int*)d_in[26];
    const int* i_ids  = (const int*)d_in[27];
    float* out = (float*)d_out;

    char* ws = (char*)d_ws;
    size_t off = 0;
    auto alloc = [&](size_t bytes) -> void* {
        void* p = ws + off;
        off += (bytes + 255) & ~(size_t)255;
        return p;
    };
    int*   map     = (int*)  alloc((size_t)NTOT * 4);
    int*   bincnt  = (int*)  alloc((size_t)2 * B * 4);
    int2*  bins    = (int2*) alloc((size_t)2 * B * CAP * 8);
    short* W0h     = (short*)alloc((size_t)2 * 65536 * 2);
    short* W1h     = (short*)alloc((size_t)2 * 65536 * 2);
    float* w2eff   = (float*)alloc(512 * 4);
    float* beff0   = (float*)alloc(512 * 4);
    float* beff1   = (float*)alloc(512 * 4);
    float* b2eff   = (float*)alloc(2 * 4);
    float* Xu      = (float*)alloc((size_t)B * 256 * 4);
    float* Xi      = (float*)alloc((size_t)B * 256 * 4);
    float* w_u     = (float*)alloc((size_t)B * 4);
    float* w_i     = (float*)alloc((size_t)B * 4);

    // 1. init (map/-1, bincnt/0) + effective weights — one dispatch
    init_weff_kernel<<<1291, 256, 0, stream>>>(
        map, bincnt,
        W0, Mw0, b0, Mb0, W1, Mw1, b1, Mb1, W2, Mw2, b2, Mb2,
        W0h, W1h, w2eff, beff0, beff1, b2eff);

    // 2. row -> slot map
    build_map_kernel<<<(B + 255) / 256, 256, 0, stream>>>(u_ids, i_ids, map);

    // 3. edge scatter into per-slot bins
    scatter_kernel<<<(E_EDGES + 255) / 256, 256, 0, stream>>>(
        A_rows, A_cols, A_vals, map, bincnt, bins);

    // 4. fused neighbor-gather + feature build
    dim3 bxgrid(B / 2, 2);
    build_x_kernel<<<bxgrid, 256, 0, stream>>>(
        u_ids, i_ids, u_catf, i_catf, u_numf, i_numf, u_cat_tab, i_cat_tab,
        numW_u, numb_u, numW_i, numb_i, embed, map, bincnt, bins, Xu, Xi);

    // 5. fused 2-layer MFMA MLP + gate
    dim3 mgrid(B / BR, 2);
    fused_mlp_kernel<<<mgrid, 256, 0, stream>>>(
        Xu, Xi, W0h, W1h, beff0, beff1, w2eff, b2eff, w_u, w_i);

    // 6. final gated dot
    dot_kernel<<<B / 4, 256, 0, stream>>>(Xu, Xi, w_u, w_i, out);
}

// Round 6
// 83.630 us; speedup vs baseline: 6.7516x; 1.0288x over previous
//
#include <hip/hip_runtime.h>
#include <math.h>

#define N_USERS 50000
#define N_ENT   200000
#define NTOT    250000
#define D       128
#define E_EDGES 2000000
#define B       8192
#define NCAT    8
#define NNUM    16
#define CAP     64    // per-slot edge bin capacity (Poisson(8) degree; P(>64)~1e-38)
#define BR      32    // batch rows per MLP block

typedef __attribute__((ext_vector_type(4))) float f32x4;
typedef __attribute__((ext_vector_type(8))) short short8;

__device__ __forceinline__ float sigf(float x) { return 1.0f / (1.0f + expf(-x)); }

// fp32 -> bf16 RNE
__device__ __forceinline__ short f2bf(float f) {
    unsigned u = __float_as_uint(f);
    unsigned r = (u + 0x7FFF + ((u >> 16) & 1)) >> 16;
    return (short)r;
}
__device__ __forceinline__ unsigned pack_bf2(float lo, float hi) {
    return ((unsigned)(unsigned short)f2bf(hi) << 16) | (unsigned short)f2bf(lo);
}
__device__ __forceinline__ float bf_lo(unsigned x) { return __uint_as_float(x << 16); }
__device__ __forceinline__ float bf_hi(unsigned x) { return __uint_as_float(x & 0xFFFF0000u); }
__device__ __forceinline__ float dot4(float4 a, float4 b) {
    return a.x * b.x + a.y * b.y + a.z * b.z + a.w * b.w;
}

// ---------------------------------------------------------------------------
// Fused init: map=-1 (62500 int4), bincnt=0 (4096 int4), masked effective weights.
__global__ __launch_bounds__(256) void init_weff_kernel(
    int* __restrict__ map, int* __restrict__ bincnt,
    const float* __restrict__ W0, const float* __restrict__ Mw0,
    const float* __restrict__ b0, const float* __restrict__ Mb0,
    const float* __restrict__ W1, const float* __restrict__ Mw1,
    const float* __restrict__ b1, const float* __restrict__ Mb1,
    const float* __restrict__ W2, const float* __restrict__ Mw2,
    const float* __restrict__ b2, const float* __restrict__ Mb2,
    short* __restrict__ W0h, short* __restrict__ W1h, float* __restrict__ w2eff,
    float* __restrict__ beff0, float* __restrict__ beff1, float* __restrict__ b2eff)
{
    int t = blockIdx.x * 256 + threadIdx.x;
    if (t < 62500) {
        ((int4*)map)[t] = make_int4(-1, -1, -1, -1);
        return;
    }
    t -= 62500;
    if (t < 4096) {
        ((int4*)bincnt)[t] = make_int4(0, 0, 0, 0);
        return;
    }
    int i = t - 4096;
    if (i < 131072) {                      // W0h: [2][256][256]
        W0h[i] = f2bf(W0[i & 65535] * sigf(Mw0[i]));
    } else if (i < 262144) {               // W1h
        int ii = i - 131072;
        W1h[ii] = f2bf(W1[ii & 65535] * sigf(Mw1[ii]));
    } else if (i < 262656) {               // w2eff: [2][256]
        int ii = i - 262144;
        w2eff[ii] = W2[ii & 255] * sigf(Mw2[ii]);
    } else if (i < 263168) {               // beff0
        int ii = i - 262656;
        beff0[ii] = b0[ii & 255] * sigf(Mb0[ii]);
    } else if (i < 263680) {               // beff1
        int ii = i - 263168;
        beff1[ii] = b1[ii & 255] * sigf(Mb1[ii]);
    } else if (i < 263682) {               // b2eff
        int ii = i - 263680;
        b2eff[ii] = b2[0] * sigf(Mb2[ii]);
    }
}

// ---------------------------------------------------------------------------
__global__ __launch_bounds__(256) void build_map_kernel(
    const int* __restrict__ uids, const int* __restrict__ iids, int* __restrict__ map)
{
    int b = blockIdx.x * 256 + threadIdx.x;
    if (b < B) {
        atomicMax(&map[uids[b] + N_ENT], b);
        atomicMax(&map[iids[b]], B + b);
    }
}

// ---------------------------------------------------------------------------
// 2 edges per thread; matched edges drop (col,val) into their slot's bin.
__global__ __launch_bounds__(256) void scatter_kernel(
    const int* __restrict__ A_rows, const int* __restrict__ A_cols,
    const float* __restrict__ A_vals, const int* __restrict__ map,
    int* __restrict__ bincnt, int2* __restrict__ bins)
{
    const int g = blockIdx.x * 256 + threadIdx.x;
    if (g >= E_EDGES / 2) return;
    const int2 rr = *(const int2*)(A_rows + 2 * g);
    const int s0 = map[rr.x];
    const int s1 = map[rr.y];
    if (s0 >= 0) {
        const int p = atomicAdd(&bincnt[s0], 1);
        if (p < CAP)
            bins[(size_t)s0 * CAP + p] = make_int2(A_cols[2 * g], __float_as_int(A_vals[2 * g]));
    }
    if (s1 >= 0) {
        const int p = atomicAdd(&bincnt[s1], 1);
        if (p < CAP)
            bins[(size_t)s1 * CAP + p] = make_int2(A_cols[2 * g + 1], __float_as_int(A_vals[2 * g + 1]));
    }
}

// ---------------------------------------------------------------------------
// Fused neighbor-gather + feature build; one (row,side) per 64-lane wave.
// Lane covers dims (2l, 2l+1) as float2. Wave-uniform values forced to SGPR
// via readfirstlane so bins/cat/num loads scalarize. First 8 neighbor loads
// issued unconditionally (clamped) for 8-deep MLP. Output X in bf16.
__global__ __launch_bounds__(256) void build_x_kernel(
    const int* __restrict__ uids, const int* __restrict__ iids,
    const int* __restrict__ u_catf, const int* __restrict__ i_catf,
    const float* __restrict__ u_numf, const float* __restrict__ i_numf,
    const float* __restrict__ u_tab, const float* __restrict__ i_tab,
    const float* __restrict__ numW_u, const float* __restrict__ numb_u,
    const float* __restrict__ numW_i, const float* __restrict__ numb_i,
    const float* __restrict__ embed, const int* __restrict__ map,
    const int* __restrict__ bincnt, const int2* __restrict__ bins,
    unsigned short* __restrict__ Xu, unsigned short* __restrict__ Xi)
{
    const int wid  = (blockIdx.x * 256 + threadIdx.x) >> 6;   // 0..16383
    const int lane = threadIdx.x & 63;
    const int side = wid & 1;
    const int b    = wid >> 1;
    const int d2   = lane * 2;

    const int* ids = side ? iids : uids;
    const int* cat_feats = side ? i_catf : u_catf;
    const float* num_feats = side ? i_numf : u_numf;
    const float* cat_table = side ? i_tab : u_tab;
    const float* numW = side ? numW_i : numW_u;
    const float* numb = side ? numb_i : numb_u;
    unsigned short* Xo = side ? Xi : Xu;

    const int uid  = __builtin_amdgcn_readfirstlane(ids[b]);
    const int grow = uid + (side ? 0 : N_ENT);
    const int slot = __builtin_amdgcn_readfirstlane(map[grow]);
    const int n    = min(__builtin_amdgcn_readfirstlane(bincnt[slot]), CAP);

    // --- issue independent loads up front ---
    const float2 ev0 = *(const float2*)(embed + (size_t)grow * D + d2);
    const int4* bl4 = (const int4*)(bins + (size_t)slot * CAP);
    const int4 ea = bl4[0], eb = bl4[1], ec = bl4[2], ed = bl4[3];   // edges 0..7
    const int4 cf0 = *(const int4*)(cat_feats + uid * NCAT);
    const int4 cf1 = *(const int4*)(cat_feats + uid * NCAT + 4);
    const float4* nf = (const float4*)(num_feats + (size_t)uid * NNUM);
    const float4 f0 = nf[0], f1 = nf[1], f2v = nf[2], f3 = nf[3];
    const float2 nbv = *(const float2*)(numb + d2);

    // --- neighbor gather: 8 unconditional clamped loads + tail loop ---
    float gx = 0.f, gy = 0.f;
    {
        int  cc[8]; float vv[8];
        cc[0]=ea.x; vv[0]=__int_as_float(ea.y); cc[1]=ea.z; vv[1]=__int_as_float(ea.w);
        cc[2]=eb.x; vv[2]=__int_as_float(eb.y); cc[3]=eb.z; vv[3]=__int_as_float(eb.w);
        cc[4]=ec.x; vv[4]=__int_as_float(ec.y); cc[5]=ec.z; vv[5]=__int_as_float(ec.w);
        cc[6]=ed.x; vv[6]=__int_as_float(ed.y); cc[7]=ed.z; vv[7]=__int_as_float(ed.w);
        float2 r[8];
#pragma unroll
        for (int j = 0; j < 8; ++j) {
            const int c = (j < n) ? cc[j] : 0;
            r[j] = *(const float2*)(embed + (size_t)c * D + d2);
        }
#pragma unroll
        for (int j = 0; j < 8; ++j) {
            const float v = (j < n) ? vv[j] : 0.f;
            gx += v * r[j].x;
            gy += v * r[j].y;
        }
    }
    const int2* bl = bins + (size_t)slot * CAP;
    for (int j = 8; j < n; j += 2) {                 // rare tail (n>8), 2-way ILP
        const int2 c0 = bl[j];
        const bool has1 = (j + 1 < n);
        const int2 c1 = has1 ? bl[j + 1] : make_int2(0, 0);
        const float2 r0 = *(const float2*)(embed + (size_t)c0.x * D + d2);
        const float2 r1 = *(const float2*)(embed + (size_t)c1.x * D + d2);
        const float v0 = __int_as_float(c0.y);
        const float v1 = has1 ? __int_as_float(c1.y) : 0.f;
        gx += v0 * r0.x + v1 * r1.x;
        gy += v0 * r0.y + v1 * r1.y;
    }

    // --- category mean: 8 independent table loads ---
    int cid[8] = {cf0.x, cf0.y, cf0.z, cf0.w, cf1.x, cf1.y, cf1.z, cf1.w};
    int cnt = 0;
#pragma unroll
    for (int f = 0; f < 8; ++f) cnt += (cid[f] > 0);
    float2 ct[8];
#pragma unroll
    for (int f = 0; f < 8; ++f)
        ct[f] = *(const float2*)(cat_table + (size_t)cid[f] * D + d2);
    float csx = 0.f, csy = 0.f;
#pragma unroll
    for (int f = 0; f < 8; ++f) { csx += ct[f].x; csy += ct[f].y; }
    const float inv = (cnt > 0) ? (1.0f / (float)cnt) : 0.0f;

    // --- numeric projection for dims d2, d2+1 ---
    const float4* w0r = (const float4*)(numW + (size_t)d2 * NNUM);
    const float4* w1r = (const float4*)(numW + (size_t)(d2 + 1) * NNUM);
    float na = nbv.x + dot4(w0r[0], f0) + dot4(w0r[1], f1) + dot4(w0r[2], f2v) + dot4(w0r[3], f3);
    float nb_ = nbv.y + dot4(w1r[0], f0) + dot4(w1r[1], f1) + dot4(w1r[2], f2v) + dot4(w1r[3], f3);

    const float fx = csx * inv + fmaxf(na, 0.f);
    const float fy = csy * inv + fmaxf(nb_, 0.f);

    // --- pack bf16 and store ---
    unsigned short* row = Xo + (size_t)b * 256;
    *(unsigned*)(row + d2)       = pack_bf2(ev0.x + gx, ev0.y + gy);
    *(unsigned*)(row + 128 + d2) = pack_bf2(fx, fy);
}

// ---------------------------------------------------------------------------
// Fused MLP (bf16 X input): H0=relu(X@W0^T+b0); H1=relu(H0@W1^T+b1);
// w = sigmoid(H1.w2+b2). BR=32 rows x 256 cols, 4 waves; LDS XOR-swizzled.
__global__ __launch_bounds__(256) void fused_mlp_kernel(
    const unsigned short* __restrict__ Xu, const unsigned short* __restrict__ Xi,
    const short* __restrict__ W0h, const short* __restrict__ W1h,
    const float* __restrict__ beff0, const float* __restrict__ beff1,
    const float* __restrict__ w2eff, const float* __restrict__ b2eff,
    float* __restrict__ w_u, float* __restrict__ w_i)
{
    const int side = blockIdx.y;               // == task
    const unsigned short* Xg = side ? Xi : Xu;
    float* wout = side ? w_i : w_u;
    const int b0 = blockIdx.x * BR;

    __shared__ __align__(16) short Xs[BR * 256];   // 16KB swizzled bf16
    __shared__ float gsum[4][BR];

    const int tid = threadIdx.x;
    const int w   = tid >> 6;
    const int l   = tid & 63;
    const int l15 = l & 15;
    const int l4  = l >> 4;

    // ---- stage X tile (bf16 global -> bf16 LDS, swizzled) ----
#pragma unroll
    for (int i = 0; i < 4; ++i) {
        const int ch  = tid + i * 256;
        const int row = ch >> 5;
        const int c8  = (ch & 31) << 3;
        const short8 hv = *(const short8*)(Xg + (size_t)(b0 + row) * 256 + c8);
        const int byte = row * 512 + ((c8 * 2) ^ ((row & 7) << 4));
        *(short8*)((char*)Xs + byte) = hv;
    }
    __syncthreads();

    const short* W0l = W0h + (size_t)side * 65536;
    const short* W1l = W1h + (size_t)side * 65536;
    const int cwbase = w * 64;

    f32x4 acc[2][4];
#pragma unroll
    for (int m = 0; m < 2; ++m)
#pragma unroll
        for (int n = 0; n < 4; ++n) acc[m][n] = (f32x4){0.f, 0.f, 0.f, 0.f};

    // ---------------- layer 0 ----------------
#pragma unroll
    for (int ks = 0; ks < 8; ++ks) {
        short8 a[2];
#pragma unroll
        for (int m = 0; m < 2; ++m) {
            const int row = m * 16 + l15;
            const int kb  = ks * 64 + l4 * 16;
            a[m] = *(const short8*)((const char*)Xs + row * 512 + (kb ^ ((row & 7) << 4)));
        }
#pragma unroll
        for (int n = 0; n < 4; ++n) {
            const short8 bb = *(const short8*)(W0l + (size_t)(cwbase + n * 16 + l15) * 256 + ks * 32 + l4 * 8);
            acc[0][n] = __builtin_amdgcn_mfma_f32_16x16x32_bf16(a[0], bb, acc[0][n], 0, 0, 0);
            acc[1][n] = __builtin_amdgcn_mfma_f32_16x16x32_bf16(a[1], bb, acc[1][n], 0, 0, 0);
        }
    }
    __syncthreads();

    // bias + relu, write H0 back into Xs (bf16, same swizzle)
#pragma unroll
    for (int n = 0; n < 4; ++n) {
        const int col = cwbase + n * 16 + l15;
        const float bia = beff0[side * 256 + col];
#pragma unroll
        for (int m = 0; m < 2; ++m)
#pragma unroll
            for (int r = 0; r < 4; ++r) {
                const float v = fmaxf(acc[m][n][r] + bia, 0.f);
                const int row = m * 16 + l4 * 4 + r;
                const int byte = row * 512 + ((col * 2) ^ ((row & 7) << 4));
                *(short*)((char*)Xs + byte) = f2bf(v);
            }
    }
    __syncthreads();

    // ---------------- layer 1 ----------------
#pragma unroll
    for (int m = 0; m < 2; ++m)
#pragma unroll
        for (int n = 0; n < 4; ++n) acc[m][n] = (f32x4){0.f, 0.f, 0.f, 0.f};

#pragma unroll
    for (int ks = 0; ks < 8; ++ks) {
        short8 a[2];
#pragma unroll
        for (int m = 0; m < 2; ++m) {
            const int row = m * 16 + l15;
            const int kb  = ks * 64 + l4 * 16;
            a[m] = *(const short8*)((const char*)Xs + row * 512 + (kb ^ ((row & 7) << 4)));
        }
#pragma unroll
        for (int n = 0; n < 4; ++n) {
            const short8 bb = *(const short8*)(W1l + (size_t)(cwbase + n * 16 + l15) * 256 + ks * 32 + l4 * 8);
            acc[0][n] = __builtin_amdgcn_mfma_f32_16x16x32_bf16(a[0], bb, acc[0][n], 0, 0, 0);
            acc[1][n] = __builtin_amdgcn_mfma_f32_16x16x32_bf16(a[1], bb, acc[1][n], 0, 0, 0);
        }
    }

    // ---------------- gate ----------------
    float w2v[4], b1v[4];
#pragma unroll
    for (int n = 0; n < 4; ++n) {
        const int col = cwbase + n * 16 + l15;
        w2v[n] = w2eff[side * 256 + col];
        b1v[n] = beff1[side * 256 + col];
    }
#pragma unroll
    for (int m = 0; m < 2; ++m)
#pragma unroll
        for (int r = 0; r < 4; ++r) {
            float s = fmaxf(acc[m][0][r] + b1v[0], 0.f) * w2v[0]
                    + fmaxf(acc[m][1][r] + b1v[1], 0.f) * w2v[1]
                    + fmaxf(acc[m][2][r] + b1v[2], 0.f) * w2v[2]
                    + fmaxf(acc[m][3][r] + b1v[3], 0.f) * w2v[3];
            s += __shfl_xor(s, 1, 16);
            s += __shfl_xor(s, 2, 16);
            s += __shfl_xor(s, 4, 16);
            s += __shfl_xor(s, 8, 16);
            if (l15 == 0) gsum[w][m * 16 + l4 * 4 + r] = s;
        }
    __syncthreads();
    if (tid < BR) {
        const float s = gsum[0][tid] + gsum[1][tid] + gsum[2][tid] + gsum[3][tid]
                      + b2eff[side];
        wout[b0 + tid] = 1.0f / (1.0f + expf(-s));
    }
}

// ---------------------------------------------------------------------------
// out[b] = sum_d (wu*eu + (1-wu)*fu) * (wi*ei + (1-wi)*fi), bf16 X inputs.
__global__ __launch_bounds__(256) void dot_kernel(
    const unsigned short* __restrict__ Xu, const unsigned short* __restrict__ Xi,
    const float* __restrict__ wu, const float* __restrict__ wi,
    float* __restrict__ out)
{
    const int tid = threadIdx.x;
    const int wv = tid >> 6, lane = tid & 63;
    const int b = blockIdx.x * 4 + wv;
    const float a = wu[b], c = wi[b];
    const unsigned short* xu = Xu + (size_t)b * 256;
    const unsigned short* xi = Xi + (size_t)b * 256;
    const unsigned ue = *(const unsigned*)(xu + 2 * lane);
    const unsigned uf = *(const unsigned*)(xu + 128 + 2 * lane);
    const unsigned ie = *(const unsigned*)(xi + 2 * lane);
    const unsigned jf = *(const unsigned*)(xi + 128 + 2 * lane);
    const float u0 = a * bf_lo(ue) + (1.f - a) * bf_lo(uf);
    const float u1 = a * bf_hi(ue) + (1.f - a) * bf_hi(uf);
    const float v0 = c * bf_lo(ie) + (1.f - c) * bf_lo(jf);
    const float v1 = c * bf_hi(ie) + (1.f - c) * bf_hi(jf);
    float s = u0 * v0 + u1 * v1;
#pragma unroll
    for (int off = 32; off > 0; off >>= 1) s += __shfl_xor(s, off, 64);
    if (lane == 0) out[b] = s;
}

// ---------------------------------------------------------------------------
extern "C" void kernel_launch(void* const* d_in, const int* in_sizes, int n_in,
                              void* d_out, int out_size, void* d_ws, size_t ws_size,
                              hipStream_t stream)
{
    const float* embed    = (const float*)d_in[0];
    const float* A_vals   = (const float*)d_in[1];
    const float* u_cat_tab= (const float*)d_in[2];
    const float* i_cat_tab= (const float*)d_in[3];
    const float* numW_u   = (const float*)d_in[4];
    const float* numb_u   = (const float*)d_in[5];
    const float* numW_i   = (const float*)d_in[6];
    const float* numb_i   = (const float*)d_in[7];
    const float* W0  = (const float*)d_in[8];
    const float* b0  = (const float*)d_in[9];
    const float* Mw0 = (const float*)d_in[10];
    const float* Mb0 = (const float*)d_in[11];
    const float* W1  = (const float*)d_in[12];
    const float* b1  = (const float*)d_in[13];
    const float* Mw1 = (const float*)d_in[14];
    const float* Mb1 = (const float*)d_in[15];
    const float* W2  = (const float*)d_in[16];
    const float* b2  = (const float*)d_in[17];
    const float* Mw2 = (const float*)d_in[18];
    const float* Mb2 = (const float*)d_in[19];
    const float* u_numf = (const float*)d_in[20];
    const float* i_numf = (const float*)d_in[21];
    const int* A_rows = (const int*)d_in[22];
    const int* A_cols = (const int*)d_in[23];
    const int* u_catf = (const int*)d_in[24];
    const int* i_catf = (const int*)d_in[25];
    const int* u_ids  = (const int*)d_in[26];
    const int* i_ids  = (const int*)d_in[27];
    float* out = (float*)d_out;

    char* ws = (char*)d_ws;
    size_t off = 0;
    auto alloc = [&](size_t bytes) -> void* {
        void* p = ws + off;
        off += (bytes + 255) & ~(size_t)255;
        return p;
    };
    int*   map     = (int*)  alloc((size_t)NTOT * 4);
    int*   bincnt  = (int*)  alloc((size_t)2 * B * 4);
    int2*  bins    = (int2*) alloc((size_t)2 * B * CAP * 8);
    short* W0h     = (short*)alloc((size_t)2 * 65536 * 2);
    short* W1h     = (short*)alloc((size_t)2 * 65536 * 2);
    float* w2eff   = (float*)alloc(512 * 4);
    float* beff0   = (float*)alloc(512 * 4);
    float* beff1   = (float*)alloc(512 * 4);
    float* b2eff   = (float*)alloc(2 * 4);
    unsigned short* Xu = (unsigned short*)alloc((size_t)B * 256 * 2);
    unsigned short* Xi = (unsigned short*)alloc((size_t)B * 256 * 2);
    float* w_u     = (float*)alloc((size_t)B * 4);
    float* w_i     = (float*)alloc((size_t)B * 4);

    // 1. init (map=-1, bincnt=0) + effective weights
    init_weff_kernel<<<1291, 256, 0, stream>>>(
        map, bincnt,
        W0, Mw0, b0, Mb0, W1, Mw1, b1, Mb1, W2, Mw2, b2, Mb2,
        W0h, W1h, w2eff, beff0, beff1, b2eff);

    // 2. row -> slot map
    build_map_kernel<<<(B + 255) / 256, 256, 0, stream>>>(u_ids, i_ids, map);

    // 3. edge scatter into per-slot bins (2 edges/thread)
    scatter_kernel<<<(E_EDGES / 2 + 255) / 256, 256, 0, stream>>>(
        A_rows, A_cols, A_vals, map, bincnt, bins);

    // 4. fused neighbor-gather + feature build (1 row-side per wave, bf16 out)
    build_x_kernel<<<(2 * B) / 4, 256, 0, stream>>>(
        u_ids, i_ids, u_catf, i_catf, u_numf, i_numf, u_cat_tab, i_cat_tab,
        numW_u, numb_u, numW_i, numb_i, embed, map, bincnt, bins, Xu, Xi);

    // 5. fused 2-layer MFMA MLP + gate
    dim3 mgrid(B / BR, 2);
    fused_mlp_kernel<<<mgrid, 256, 0, stream>>>(
        Xu, Xi, W0h, W1h, beff0, beff1, w2eff, b2eff, w_u, w_i);

    // 6. final gated dot
    dot_kernel<<<B / 4, 256, 0, stream>>>(Xu, Xi, w_u, w_i, out);
}